// Round 1
// baseline (6581.962 us; speedup 1.0000x reference)
//
#include <hip/hip_runtime.h>
#include <hip/hip_bf16.h>

typedef __hip_bfloat16 bf16;

#define N_USER 200000
#define N_ITEM 100000
#define NEDGE  1000000
#define HID    64

// ---------------------------------------------------------------------------
// Dtype-agnostic access: harness data may be fp32 or bf16 (detected at runtime
// each launch — no static state, graph-safe). Offsets are ELEMENT offsets.
// ---------------------------------------------------------------------------
__device__ __forceinline__ float bf2f(unsigned int u) {
    unsigned int x = u << 16;
    float f; __builtin_memcpy(&f, &x, 4); return f;
}
__device__ __forceinline__ float ldf(const void* p, long i, int isf32) {
    if (isf32) return ((const float*)p)[i];
    return bf2f(((const unsigned short*)p)[i]);
}
__device__ __forceinline__ void stf(void* p, long i, int isf32, float v) {
    if (isf32) ((float*)p)[i] = v;
    else       ((bf16*)p)[i] = (bf16)v;
}
// Load one edge_attr row (16 elems) vectorized: fp32 = 4x float4, bf16 = 2x int4.
__device__ __forceinline__ void load_row16(const void* ea, long e, int isf32, float* v) {
    if (isf32) {
        const float4* p = (const float4*)((const float*)ea + e * 16);
        float4 a = p[0], b = p[1], c = p[2], d = p[3];
        v[0]=a.x; v[1]=a.y; v[2]=a.z; v[3]=a.w;
        v[4]=b.x; v[5]=b.y; v[6]=b.z; v[7]=b.w;
        v[8]=c.x; v[9]=c.y; v[10]=c.z; v[11]=c.w;
        v[12]=d.x; v[13]=d.y; v[14]=d.z; v[15]=d.w;
    } else {
        const int4* q = (const int4*)((const unsigned short*)ea + e * 16);
        int4 s0 = q[0], s1 = q[1];
        unsigned int w;
        w=(unsigned)s0.x; v[0]=bf2f(w & 0xffff); v[1]=bf2f(w >> 16);
        w=(unsigned)s0.y; v[2]=bf2f(w & 0xffff); v[3]=bf2f(w >> 16);
        w=(unsigned)s0.z; v[4]=bf2f(w & 0xffff); v[5]=bf2f(w >> 16);
        w=(unsigned)s0.w; v[6]=bf2f(w & 0xffff); v[7]=bf2f(w >> 16);
        w=(unsigned)s1.x; v[8]=bf2f(w & 0xffff); v[9]=bf2f(w >> 16);
        w=(unsigned)s1.y; v[10]=bf2f(w & 0xffff); v[11]=bf2f(w >> 16);
        w=(unsigned)s1.z; v[12]=bf2f(w & 0xffff); v[13]=bf2f(w >> 16);
        w=(unsigned)s1.w; v[14]=bf2f(w & 0xffff); v[15]=bf2f(w >> 16);
    }
}

// fp32-vs-bf16 detector (R3-verified): fp32's interleaved mantissa halves hit
// biased exp >= 137 with p~0.46/word; true bf16 N(0,1) never does.
// Parallelized over one wave (old version was 512 serial iters on 1 lane).
__global__ void detect_kernel(const void* __restrict__ x, int* __restrict__ flag) {
    const unsigned short* p = (const unsigned short*)x;
    int f = 0;
    for (int k = threadIdx.x; k < 512; k += 64) {
        int ex = (p[k] >> 7) & 0xFF;
        if (ex >= 137) f = 1;
    }
    unsigned long long b = __ballot(f != 0);
    if (threadIdx.x == 0) *flag = (b != 0ULL) ? 1 : 0;
}

// ---------------------------------------------------------------------------
// CSR build: fused dual histogram -> shuffle-scan (both arrays, 2 WGs) ->
// fused dual scatter. cursor doubles as the degree array.
// ---------------------------------------------------------------------------
__global__ __launch_bounds__(256) void hist2_kernel(
    const int* __restrict__ src, const int* __restrict__ dst,
    int* __restrict__ cnt_u, int* __restrict__ cnt_i, int E)
{
    int e = blockIdx.x * 256 + threadIdx.x;
    if (e < E) {
        atomicAdd(&cnt_u[src[e]], 1);
        atomicAdd(&cnt_i[dst[e]], 1);
    }
}

__device__ __forceinline__ int wave_incl_scan(int v, int lane) {
#pragma unroll
    for (int off = 1; off < 64; off <<= 1) {
        int t = __shfl_up(v, off, 64);
        if (lane >= off) v += t;
    }
    return v;
}

// block 0 scans the item degrees, block 1 the user degrees.
// 2 barriers per 8192-chunk (wave shuffle scan), vs 20 in the ladder version.
__global__ __launch_bounds__(1024) void scan_kernel(
    int* __restrict__ deg_i, int* __restrict__ rp_i, int Ni,
    int* __restrict__ deg_u, int* __restrict__ rp_u, int Nu)
{
    __shared__ int swsum[16];
    __shared__ int s_carry;
    int* deg    = (blockIdx.x == 0) ? deg_i : deg_u;
    int* rowptr = (blockIdx.x == 0) ? rp_i  : rp_u;
    int N       = (blockIdx.x == 0) ? Ni    : Nu;
    int tid = threadIdx.x, lane = tid & 63, wid = tid >> 6;
    if (tid == 0) s_carry = 0;
    int grand = 0;
    for (int base = 0; base < N; base += 8192) {
        int i0 = base + tid * 8;
        int v[8]; int tot = 0;
#pragma unroll
        for (int k = 0; k < 8; k++) { int i = i0 + k; v[k] = (i < N) ? deg[i] : 0; tot += v[k]; }
        int incl = wave_incl_scan(tot, lane);
        if (lane == 63) swsum[wid] = incl;
        __syncthreads();                       // A: swsum ready, s_carry stable
        int carry = s_carry;
        int wbase = 0;
        for (int jw = 0; jw < wid; jw++) wbase += swsum[jw];
        int exc = carry + wbase + incl - tot;
#pragma unroll
        for (int k = 0; k < 8; k++) {
            int i = i0 + k;
            if (i < N) { rowptr[i] = exc; deg[i] = exc; }   // deg becomes cursor
            exc += v[k];
        }
        __syncthreads();                       // B: all reads of s_carry/swsum done
        if (tid == 1023) { s_carry = exc; grand = exc; }    // exc = carry + chunk total
    }
    if (tid == 1023) rowptr[N] = grand;
}

__global__ __launch_bounds__(256) void scatter2_kernel(
    const int* __restrict__ src, const int* __restrict__ dst,
    int* __restrict__ cur_u, int* __restrict__ cur_i,
    int2* __restrict__ perm_u, int2* __restrict__ perm_i, int E)
{
    int e = blockIdx.x * 256 + threadIdx.x;
    if (e >= E) return;
    int s = src[e], d = dst[e];
    int pu = atomicAdd(&cur_u[s], 1);
    perm_u[pu] = make_int2(e, d);
    int pi = atomicAdd(&cur_i[d], 1);
    perm_i[pi] = make_int2(e, s);
}

// ---------------------------------------------------------------------------
// Input projection (grid-stride): out[n,c] = relu(x[n,:]@W[:,c] + b[c]).
// Block = 4 rows x 64 cols; W fp32 in LDS staged once per block.
// ---------------------------------------------------------------------------
template<int K>
__global__ __launch_bounds__(256) void proj_kernel(
    const void* __restrict__ x, const void* __restrict__ W,
    const void* __restrict__ b, float* __restrict__ out, int N,
    const int* __restrict__ flagp)
{
    __shared__ float Ws[K * 64];
    __shared__ float xs[4][K];
    int isf32 = *flagp;
    int tid = threadIdx.x;
    for (int i = tid; i < K * 64; i += 256) Ws[i] = ldf(W, i, isf32);
    int r = tid >> 6, c = tid & 63;
    float bc = ldf(b, c, isf32);
    for (int row0 = blockIdx.x * 4; row0 < N; row0 += gridDim.x * 4) {
        __syncthreads();   // WAR on xs (and Ws staging, first iter)
        for (int i = tid; i < 4 * K; i += 256) {
            int rr = i / K, k = i - rr * K;
            int row = row0 + rr;
            xs[rr][k] = (row < N) ? ldf(x, (long)row * K + k, isf32) : 0.f;
        }
        __syncthreads();
        int row = row0 + r;
        float acc = bc;
#pragma unroll
        for (int k = 0; k < K; k++) acc = fmaf(xs[r][k], Ws[k * 64 + c], acc);
        if (row < N) out[(long)row * 64 + c] = fmaxf(acc, 0.f);
    }
}

// ---------------------------------------------------------------------------
// Phase A — edge aggregation only (split from the old fused conv):
//   agg[n,c] = (1+eps)*h_dst[n,c] + sum_{j in CSR[n]} relu(h_src[src_j][c]
//              + ea[e_j]@We[:,c] + be[c])
// One wave per node, ZERO barriers in the loop (waves fully independent -> no
// degree-variance coupling), LDS only 4.3 KB -> __launch_bounds__(256,8)
// gives 8 blocks/CU = 32 waves/CU (2x the fused kernel) to hide gather latency.
// ---------------------------------------------------------------------------
__global__ __launch_bounds__(256, 8) void agg_kernel(
    const float* __restrict__ h_src, const float* __restrict__ h_dst,
    const int* __restrict__ rowptr, const int2* __restrict__ perm,
    const void* __restrict__ ea,
    const void* __restrict__ We, long weoff, const void* __restrict__ be, long beoff,
    const void* __restrict__ eps, int conv,
    float* __restrict__ agg, int N, const int* __restrict__ flagp)
{
    __shared__ float Wes[16 * 64];
    __shared__ float bes[64];
    int isf32 = *flagp;
    int tid = threadIdx.x;
    for (int i = tid; i < 1024; i += 256) Wes[i] = ldf(We, weoff + i, isf32);
    if (tid < 64) bes[tid] = ldf(be, beoff + tid, isf32);
    __syncthreads();
    float eps1 = 1.f + ldf(eps, conv, isf32);
    int w = tid >> 6, c = tid & 63;
    float bec = bes[c];

    for (int n = blockIdx.x * 4 + w; n < N; n += gridDim.x * 4) {
        float hv = h_dst[(long)n * 64 + c];
        float acc = 0.f;
        int jb = rowptr[n], je = rowptr[n + 1];
        int j = jb;
        for (; j + 4 <= je; j += 4) {
            int2 p0 = perm[j], p1 = perm[j+1], p2 = perm[j+2], p3 = perm[j+3];
            float a0[16], a1[16], a2[16], a3[16];
            load_row16(ea, p0.x, isf32, a0);
            load_row16(ea, p1.x, isf32, a1);
            load_row16(ea, p2.x, isf32, a2);
            load_row16(ea, p3.x, isf32, a3);
            float h0 = h_src[(long)p0.y * 64 + c];
            float h1 = h_src[(long)p1.y * 64 + c];
            float h2 = h_src[(long)p2.y * 64 + c];
            float h3 = h_src[(long)p3.y * 64 + c];
            float m0 = bec, m1 = bec, m2 = bec, m3 = bec;
#pragma unroll
            for (int k = 0; k < 16; k++) {
                float wv = Wes[k * 64 + c];
                m0 = fmaf(a0[k], wv, m0); m1 = fmaf(a1[k], wv, m1);
                m2 = fmaf(a2[k], wv, m2); m3 = fmaf(a3[k], wv, m3);
            }
            acc += fmaxf(m0 + h0, 0.f); acc += fmaxf(m1 + h1, 0.f);
            acc += fmaxf(m2 + h2, 0.f); acc += fmaxf(m3 + h3, 0.f);
        }
        for (; j < je; j++) {
            int2 p0 = perm[j];
            float a0[16];
            load_row16(ea, p0.x, isf32, a0);
            float h0 = h_src[(long)p0.y * 64 + c];
            float m0 = bec;
#pragma unroll
            for (int k = 0; k < 16; k++) m0 = fmaf(a0[k], Wes[k * 64 + c], m0);
            acc += fmaxf(m0 + h0, 0.f);
        }
        agg[(long)n * 64 + c] = eps1 * hv + acc;
    }
}

// ---------------------------------------------------------------------------
// Phase B — node MLP (streaming, coalesced, in-place safe):
//   o = relu( relu(v@W1+b1) @ W2 + b2 )  (+ resid[n] if RESID)
// 8 nodes per block-iteration (2 per wave) to amortize barriers.
// ---------------------------------------------------------------------------
template<int RESID>
__global__ __launch_bounds__(256, 4) void mlp_kernel(
    const float* __restrict__ vin, const float* __restrict__ resid,
    const void* __restrict__ W1, const void* __restrict__ b1,
    const void* __restrict__ W2, const void* __restrict__ b2, long woff, long boff,
    float* __restrict__ outf, void* __restrict__ outv, long outoff,
    int N, const int* __restrict__ flagp)
{
    __shared__ float W1s[4096], W2s[4096];
    __shared__ float b1s[64], b2s[64];
    __shared__ float vs[8][64], ts[8][64];
    int isf32 = *flagp;
    int tid = threadIdx.x;
    for (int i = tid; i < 4096; i += 256) {
        W1s[i] = ldf(W1, woff + i, isf32);
        W2s[i] = ldf(W2, woff + i, isf32);
    }
    if (tid < 64) {
        b1s[tid] = ldf(b1, boff + tid, isf32);
        b2s[tid] = ldf(b2, boff + tid, isf32);
    }
    int w = tid >> 6, c = tid & 63;
    int na_off = 2 * w, nb_off = 2 * w + 1;
    for (long n0 = (long)blockIdx.x * 8; n0 < N; n0 += (long)gridDim.x * 8) {
        __syncthreads();   // WAR on vs/ts from prev iter (and weight staging, iter 0)
        for (int i = tid; i < 512; i += 256) {
            long n = n0 + (i >> 6);
            vs[i >> 6][i & 63] = (n < N) ? vin[n * 64 + (i & 63)] : 0.f;
        }
        __syncthreads();
        float ta = b1s[c], tb = b1s[c];
#pragma unroll
        for (int k = 0; k < 64; k++) {
            float wv = W1s[k * 64 + c];
            ta = fmaf(vs[na_off][k], wv, ta);
            tb = fmaf(vs[nb_off][k], wv, tb);
        }
        ts[na_off][c] = fmaxf(ta, 0.f);
        ts[nb_off][c] = fmaxf(tb, 0.f);
        __syncthreads();
        float oa = b2s[c], ob = b2s[c];
#pragma unroll
        for (int k = 0; k < 64; k++) {
            float wv = W2s[k * 64 + c];
            oa = fmaf(ts[na_off][k], wv, oa);
            ob = fmaf(ts[nb_off][k], wv, ob);
        }
        oa = fmaxf(oa, 0.f); ob = fmaxf(ob, 0.f);
        long na = n0 + na_off, nb = n0 + nb_off;
        if (na < N) {
            float o = oa;
            if (RESID) o += resid[na * 64 + c];
            if (outv) stf(outv, outoff + na * 64 + c, isf32, o);
            else      outf[na * 64 + c] = o;
        }
        if (nb < N) {
            float o = ob;
            if (RESID) o += resid[nb * 64 + c];
            if (outv) stf(outv, outoff + nb * 64 + c, isf32, o);
            else      outf[nb * 64 + c] = o;
        }
    }
}

extern "C" void kernel_launch(void* const* d_in, const int* in_sizes, int n_in,
                              void* d_out, int out_size, void* d_ws, size_t ws_size,
                              hipStream_t stream)
{
    const void* x_user    = d_in[0];
    const void* x_item    = d_in[1];
    const void* edge_attr = d_in[2];
    const int*  src_idx   = (const int*)d_in[3];
    const int*  dst_idx   = (const int*)d_in[4];
    const void* Wp_user   = d_in[5];
    const void* bp_user   = d_in[6];
    const void* Wp_item   = d_in[7];
    const void* bp_item   = d_in[8];
    const void* eps       = d_in[9];
    const void* We        = d_in[10];
    const void* be        = d_in[11];
    const void* W1        = d_in[12];
    const void* b1        = d_in[13];
    const void* W2        = d_in[14];
    const void* b2        = d_in[15];

    // Workspace layout (4B elements, 256-aligned): same footprint as before.
    // Layer-1 agg outputs reuse h_u / h_i (dead after the layer-0 agg pass).
    float* ws   = (float*)d_ws;
    int*  flag  = (int*)d_ws;
    float* h_u  = ws + 256;             // 12.8M
    float* h_i  = h_u + 12800000;       //  6.4M
    float* h_u2 = h_i + 6400000;        // 12.8M
    float* h_i2 = h_u2 + 12800000;      //  6.4M
    int* rowptr_i = (int*)(h_i2 + 6400000);   // 100,001 (pad 100,096)
    int* cursor_i = rowptr_i + 100096;        // 100,000 (pad 100,096); also deg
    int2* perm_i  = (int2*)(cursor_i + 100096);  // 1M int2
    int* rowptr_u = (int*)(perm_i + 1000000); // 200,001 (pad 200,192)
    int* cursor_u = rowptr_u + 200192;        // 200,000 (pad 200,192)
    int2* perm_u  = (int2*)(cursor_u + 200192);  // 1M int2

    const int EG = (NEDGE + 255) / 256;

    detect_kernel<<<1, 64, 0, stream>>>(x_user, flag);

    // CSR build: both relations in single passes over the edge list.
    hipMemsetAsync(cursor_i, 0, N_ITEM * sizeof(int), stream);
    hipMemsetAsync(cursor_u, 0, N_USER * sizeof(int), stream);
    hist2_kernel<<<EG, 256, 0, stream>>>(src_idx, dst_idx, cursor_u, cursor_i, NEDGE);
    scan_kernel<<<2, 1024, 0, stream>>>(cursor_i, rowptr_i, N_ITEM,
                                        cursor_u, rowptr_u, N_USER);
    scatter2_kernel<<<EG, 256, 0, stream>>>(src_idx, dst_idx, cursor_u, cursor_i,
                                            perm_u, perm_i, NEDGE);

    // input projections
    proj_kernel<128><<<1024, 256, 0, stream>>>(x_user, Wp_user, bp_user, h_u, N_USER, flag);
    proj_kernel<64><<<1024, 256, 0, stream>>>(x_item, Wp_item, bp_item, h_i, N_ITEM, flag);

    // ---- layer 0 (no residual): aggs read (h_u,h_i) snapshot, write h_*2;
    //      MLPs run in-place on h_*2.
    agg_kernel<<<2048, 256, 0, stream>>>(h_u, h_i, rowptr_i, perm_i, edge_attr,
        We, 0 * 1024, be, 0 * 64, eps, 0, h_i2, N_ITEM, flag);
    agg_kernel<<<2048, 256, 0, stream>>>(h_i, h_u, rowptr_u, perm_u, edge_attr,
        We, 1 * 1024, be, 1 * 64, eps, 1, h_u2, N_USER, flag);
    mlp_kernel<0><<<1024, 256, 0, stream>>>(h_i2, nullptr,
        W1, b1, W2, b2, 0 * 4096, 0 * 64, h_i2, nullptr, 0, N_ITEM, flag);
    mlp_kernel<0><<<1024, 256, 0, stream>>>(h_u2, nullptr,
        W1, b1, W2, b2, 1 * 4096, 1 * 64, h_u2, nullptr, 0, N_USER, flag);

    // ---- layer 1 (residual): aggs read (h_u2,h_i2), write into dead h_i/h_u;
    //      MLPs add resid = h_*2 and store to d_out in the flagged dtype.
    agg_kernel<<<2048, 256, 0, stream>>>(h_u2, h_i2, rowptr_i, perm_i, edge_attr,
        We, 2 * 1024, be, 2 * 64, eps, 2, h_i, N_ITEM, flag);
    agg_kernel<<<2048, 256, 0, stream>>>(h_i2, h_u2, rowptr_u, perm_u, edge_attr,
        We, 3 * 1024, be, 3 * 64, eps, 3, h_u, N_USER, flag);
    mlp_kernel<1><<<1024, 256, 0, stream>>>(h_i, h_i2,
        W1, b1, W2, b2, 2 * 4096, 2 * 64, nullptr, d_out, (long)N_USER * HID, N_ITEM, flag);
    mlp_kernel<1><<<1024, 256, 0, stream>>>(h_u, h_u2,
        W1, b1, W2, b2, 3 * 4096, 3 * 64, nullptr, d_out, 0, N_USER, flag);
}

// Round 3
// 3418.439 us; speedup vs baseline: 1.9254x; 1.9254x over previous
//
#include <hip/hip_runtime.h>
#include <hip/hip_bf16.h>

typedef __hip_bfloat16 bf16;

#define N_USER 200000
#define N_ITEM 100000
#define NEDGE  1000000
#define HID    64

// ---------------------------------------------------------------------------
// Dtype-agnostic access: harness data may be fp32 or bf16 (detected at runtime
// each launch — no static state, graph-safe). Offsets are ELEMENT offsets.
// ---------------------------------------------------------------------------
__device__ __forceinline__ float bf2f(unsigned int u) {
    unsigned int x = u << 16;
    float f; __builtin_memcpy(&f, &x, 4); return f;
}
__device__ __forceinline__ float ldf(const void* p, long i, int isf32) {
    if (isf32) return ((const float*)p)[i];
    return bf2f(((const unsigned short*)p)[i]);
}
__device__ __forceinline__ void stf(void* p, long i, int isf32, float v) {
    if (isf32) ((float*)p)[i] = v;
    else       ((bf16*)p)[i] = (bf16)v;
}
// Load one edge_attr row (16 elems) vectorized: fp32 = 4x float4, bf16 = 2x int4.
__device__ __forceinline__ void load_row16(const void* ea, long e, int isf32, float* v) {
    if (isf32) {
        const float4* p = (const float4*)((const float*)ea + e * 16);
        float4 a = p[0], b = p[1], c = p[2], d = p[3];
        v[0]=a.x; v[1]=a.y; v[2]=a.z; v[3]=a.w;
        v[4]=b.x; v[5]=b.y; v[6]=b.z; v[7]=b.w;
        v[8]=c.x; v[9]=c.y; v[10]=c.z; v[11]=c.w;
        v[12]=d.x; v[13]=d.y; v[14]=d.z; v[15]=d.w;
    } else {
        const int4* q = (const int4*)((const unsigned short*)ea + e * 16);
        int4 s0 = q[0], s1 = q[1];
        unsigned int w;
        w=(unsigned)s0.x; v[0]=bf2f(w & 0xffff); v[1]=bf2f(w >> 16);
        w=(unsigned)s0.y; v[2]=bf2f(w & 0xffff); v[3]=bf2f(w >> 16);
        w=(unsigned)s0.z; v[4]=bf2f(w & 0xffff); v[5]=bf2f(w >> 16);
        w=(unsigned)s0.w; v[6]=bf2f(w & 0xffff); v[7]=bf2f(w >> 16);
        w=(unsigned)s1.x; v[8]=bf2f(w & 0xffff); v[9]=bf2f(w >> 16);
        w=(unsigned)s1.y; v[10]=bf2f(w & 0xffff); v[11]=bf2f(w >> 16);
        w=(unsigned)s1.z; v[12]=bf2f(w & 0xffff); v[13]=bf2f(w >> 16);
        w=(unsigned)s1.w; v[14]=bf2f(w & 0xffff); v[15]=bf2f(w >> 16);
    }
}

// fp32-vs-bf16 detector (R3-verified): fp32's interleaved mantissa halves hit
// biased exp >= 137 with p~0.46/word; true bf16 N(0,1) never does.
__global__ void detect_kernel(const void* __restrict__ x, int* __restrict__ flag) {
    const unsigned short* p = (const unsigned short*)x;
    int f = 0;
    for (int k = threadIdx.x; k < 512; k += 64) {
        int ex = (p[k] >> 7) & 0xFF;
        if (ex >= 137) f = 1;
    }
    unsigned long long b = __ballot(f != 0);
    if (threadIdx.x == 0) *flag = (b != 0ULL) ? 1 : 0;
}

// ---------------------------------------------------------------------------
// CSR build: fused dual histogram -> shuffle-scan (both arrays, 2 WGs) ->
// fused dual scatter. cursor doubles as the degree array.
// ---------------------------------------------------------------------------
__global__ __launch_bounds__(256) void hist2_kernel(
    const int* __restrict__ src, const int* __restrict__ dst,
    int* __restrict__ cnt_u, int* __restrict__ cnt_i, int E)
{
    int e = blockIdx.x * 256 + threadIdx.x;
    if (e < E) {
        atomicAdd(&cnt_u[src[e]], 1);
        atomicAdd(&cnt_i[dst[e]], 1);
    }
}

__device__ __forceinline__ int wave_incl_scan(int v, int lane) {
#pragma unroll
    for (int off = 1; off < 64; off <<= 1) {
        int t = __shfl_up(v, off, 64);
        if (lane >= off) v += t;
    }
    return v;
}

// block 0 scans the item degrees, block 1 the user degrees.
__global__ __launch_bounds__(1024) void scan_kernel(
    int* __restrict__ deg_i, int* __restrict__ rp_i, int Ni,
    int* __restrict__ deg_u, int* __restrict__ rp_u, int Nu)
{
    __shared__ int swsum[16];
    __shared__ int s_carry;
    int* deg    = (blockIdx.x == 0) ? deg_i : deg_u;
    int* rowptr = (blockIdx.x == 0) ? rp_i  : rp_u;
    int N       = (blockIdx.x == 0) ? Ni    : Nu;
    int tid = threadIdx.x, lane = tid & 63, wid = tid >> 6;
    if (tid == 0) s_carry = 0;
    int grand = 0;
    for (int base = 0; base < N; base += 8192) {
        int i0 = base + tid * 8;
        int v[8]; int tot = 0;
#pragma unroll
        for (int k = 0; k < 8; k++) { int i = i0 + k; v[k] = (i < N) ? deg[i] : 0; tot += v[k]; }
        int incl = wave_incl_scan(tot, lane);
        if (lane == 63) swsum[wid] = incl;
        __syncthreads();                       // A: swsum ready, s_carry stable
        int carry = s_carry;
        int wbase = 0;
        for (int jw = 0; jw < wid; jw++) wbase += swsum[jw];
        int exc = carry + wbase + incl - tot;
#pragma unroll
        for (int k = 0; k < 8; k++) {
            int i = i0 + k;
            if (i < N) { rowptr[i] = exc; deg[i] = exc; }   // deg becomes cursor
            exc += v[k];
        }
        __syncthreads();                       // B: all reads of s_carry/swsum done
        if (tid == 1023) { s_carry = exc; grand = exc; }    // exc = carry + chunk total
    }
    if (tid == 1023) rowptr[N] = grand;
}

__global__ __launch_bounds__(256) void scatter2_kernel(
    const int* __restrict__ src, const int* __restrict__ dst,
    int* __restrict__ cur_u, int* __restrict__ cur_i,
    int2* __restrict__ perm_u, int2* __restrict__ perm_i, int E)
{
    int e = blockIdx.x * 256 + threadIdx.x;
    if (e >= E) return;
    int s = src[e], d = dst[e];
    int pu = atomicAdd(&cur_u[s], 1);
    perm_u[pu] = make_int2(e, d);
    int pi = atomicAdd(&cur_i[d], 1);
    perm_i[pi] = make_int2(e, s);
}

// ---------------------------------------------------------------------------
// Input projection (grid-stride): out[n,c] = relu(x[n,:]@W[:,c] + b[c]).
// ---------------------------------------------------------------------------
template<int K>
__global__ __launch_bounds__(256) void proj_kernel(
    const void* __restrict__ x, const void* __restrict__ W,
    const void* __restrict__ b, float* __restrict__ out, int N,
    const int* __restrict__ flagp)
{
    __shared__ float Ws[K * 64];
    __shared__ float xs[4][K];
    int isf32 = *flagp;
    int tid = threadIdx.x;
    for (int i = tid; i < K * 64; i += 256) Ws[i] = ldf(W, i, isf32);
    int r = tid >> 6, c = tid & 63;
    float bc = ldf(b, c, isf32);
    for (int row0 = blockIdx.x * 4; row0 < N; row0 += gridDim.x * 4) {
        __syncthreads();   // WAR on xs (and Ws staging, first iter)
        for (int i = tid; i < 4 * K; i += 256) {
            int rr = i / K, k = i - rr * K;
            int row = row0 + rr;
            xs[rr][k] = (row < N) ? ldf(x, (long)row * K + k, isf32) : 0.f;
        }
        __syncthreads();
        int row = row0 + r;
        float acc = bc;
#pragma unroll
        for (int k = 0; k < K; k++) acc = fmaf(xs[r][k], Ws[k * 64 + c], acc);
        if (row < N) out[(long)row * 64 + c] = fmaxf(acc, 0.f);
    }
}

// ---------------------------------------------------------------------------
// Phase A — edge aggregation only:
//   agg[n,c] = (1+eps)*h_dst[n,c] + sum_{j in CSR[n]} relu(h_src[src_j][c]
//              + ea[e_j]@We[:,c] + be[c])
// One wave per node, zero barriers in the loop. LDS 4.6 KB.
// __launch_bounds__(256, 4): the R0-proven bound for this inner loop — 64
// VGPRs, NO SPILL. (256,8) forced VGPR=32 and spilled the a0..a3 arrays to
// scratch: 3.7 GB of scratch traffic per dispatch, 3x slower than fused.
// Runtime occupancy is set by actual VGPR/LDS: at 64 VGPR + 4.6 KB LDS the
// HW allows 8 blocks/CU = 32 waves/CU.
// ---------------------------------------------------------------------------
__global__ __launch_bounds__(256, 4) void agg_kernel(
    const float* __restrict__ h_src, const float* __restrict__ h_dst,
    const int* __restrict__ rowptr, const int2* __restrict__ perm,
    const void* __restrict__ ea,
    const void* __restrict__ We, long weoff, const void* __restrict__ be, long beoff,
    const void* __restrict__ eps, int conv,
    float* __restrict__ agg, int N, const int* __restrict__ flagp)
{
    __shared__ float Wes[16 * 64];
    __shared__ float bes[64];
    int isf32 = *flagp;
    int tid = threadIdx.x;
    for (int i = tid; i < 1024; i += 256) Wes[i] = ldf(We, weoff + i, isf32);
    if (tid < 64) bes[tid] = ldf(be, beoff + tid, isf32);
    __syncthreads();
    float eps1 = 1.f + ldf(eps, conv, isf32);
    int w = tid >> 6, c = tid & 63;
    float bec = bes[c];

    for (int n = blockIdx.x * 4 + w; n < N; n += gridDim.x * 4) {
        float hv = h_dst[(long)n * 64 + c];
        float acc = 0.f;
        int jb = rowptr[n], je = rowptr[n + 1];
        int j = jb;
        for (; j + 4 <= je; j += 4) {
            int2 p0 = perm[j], p1 = perm[j+1], p2 = perm[j+2], p3 = perm[j+3];
            float a0[16], a1[16], a2[16], a3[16];
            load_row16(ea, p0.x, isf32, a0);
            load_row16(ea, p1.x, isf32, a1);
            load_row16(ea, p2.x, isf32, a2);
            load_row16(ea, p3.x, isf32, a3);
            float h0 = h_src[(long)p0.y * 64 + c];
            float h1 = h_src[(long)p1.y * 64 + c];
            float h2 = h_src[(long)p2.y * 64 + c];
            float h3 = h_src[(long)p3.y * 64 + c];
            float m0 = bec, m1 = bec, m2 = bec, m3 = bec;
#pragma unroll
            for (int k = 0; k < 16; k++) {
                float wv = Wes[k * 64 + c];
                m0 = fmaf(a0[k], wv, m0); m1 = fmaf(a1[k], wv, m1);
                m2 = fmaf(a2[k], wv, m2); m3 = fmaf(a3[k], wv, m3);
            }
            acc += fmaxf(m0 + h0, 0.f); acc += fmaxf(m1 + h1, 0.f);
            acc += fmaxf(m2 + h2, 0.f); acc += fmaxf(m3 + h3, 0.f);
        }
        for (; j < je; j++) {
            int2 p0 = perm[j];
            float a0[16];
            load_row16(ea, p0.x, isf32, a0);
            float h0 = h_src[(long)p0.y * 64 + c];
            float m0 = bec;
#pragma unroll
            for (int k = 0; k < 16; k++) m0 = fmaf(a0[k], Wes[k * 64 + c], m0);
            acc += fmaxf(m0 + h0, 0.f);
        }
        agg[(long)n * 64 + c] = eps1 * hv + acc;
    }
}

// ---------------------------------------------------------------------------
// Phase B — node MLP (streaming, coalesced, in-place safe):
//   o = relu( relu(v@W1+b1) @ W2 + b2 )  (+ resid[n] if RESID)
// ---------------------------------------------------------------------------
template<int RESID>
__global__ __launch_bounds__(256, 4) void mlp_kernel(
    const float* __restrict__ vin, const float* __restrict__ resid,
    const void* __restrict__ W1, const void* __restrict__ b1,
    const void* __restrict__ W2, const void* __restrict__ b2, long woff, long boff,
    float* __restrict__ outf, void* __restrict__ outv, long outoff,
    int N, const int* __restrict__ flagp)
{
    __shared__ float W1s[4096], W2s[4096];
    __shared__ float b1s[64], b2s[64];
    __shared__ float vs[8][64], ts[8][64];
    int isf32 = *flagp;
    int tid = threadIdx.x;
    for (int i = tid; i < 4096; i += 256) {
        W1s[i] = ldf(W1, woff + i, isf32);
        W2s[i] = ldf(W2, woff + i, isf32);
    }
    if (tid < 64) {
        b1s[tid] = ldf(b1, boff + tid, isf32);
        b2s[tid] = ldf(b2, boff + tid, isf32);
    }
    int w = tid >> 6, c = tid & 63;
    int na_off = 2 * w, nb_off = 2 * w + 1;
    for (long n0 = (long)blockIdx.x * 8; n0 < N; n0 += (long)gridDim.x * 8) {
        __syncthreads();   // WAR on vs/ts from prev iter (and weight staging, iter 0)
        for (int i = tid; i < 512; i += 256) {
            long n = n0 + (i >> 6);
            vs[i >> 6][i & 63] = (n < N) ? vin[n * 64 + (i & 63)] : 0.f;
        }
        __syncthreads();
        float ta = b1s[c], tb = b1s[c];
#pragma unroll
        for (int k = 0; k < 64; k++) {
            float wv = W1s[k * 64 + c];
            ta = fmaf(vs[na_off][k], wv, ta);
            tb = fmaf(vs[nb_off][k], wv, tb);
        }
        ts[na_off][c] = fmaxf(ta, 0.f);
        ts[nb_off][c] = fmaxf(tb, 0.f);
        __syncthreads();
        float oa = b2s[c], ob = b2s[c];
#pragma unroll
        for (int k = 0; k < 64; k++) {
            float wv = W2s[k * 64 + c];
            oa = fmaf(ts[na_off][k], wv, oa);
            ob = fmaf(ts[nb_off][k], wv, ob);
        }
        oa = fmaxf(oa, 0.f); ob = fmaxf(ob, 0.f);
        long na = n0 + na_off, nb = n0 + nb_off;
        if (na < N) {
            float o = oa;
            if (RESID) o += resid[na * 64 + c];
            if (outv) stf(outv, outoff + na * 64 + c, isf32, o);
            else      outf[na * 64 + c] = o;
        }
        if (nb < N) {
            float o = ob;
            if (RESID) o += resid[nb * 64 + c];
            if (outv) stf(outv, outoff + nb * 64 + c, isf32, o);
            else      outf[nb * 64 + c] = o;
        }
    }
}

extern "C" void kernel_launch(void* const* d_in, const int* in_sizes, int n_in,
                              void* d_out, int out_size, void* d_ws, size_t ws_size,
                              hipStream_t stream)
{
    const void* x_user    = d_in[0];
    const void* x_item    = d_in[1];
    const void* edge_attr = d_in[2];
    const int*  src_idx   = (const int*)d_in[3];
    const int*  dst_idx   = (const int*)d_in[4];
    const void* Wp_user   = d_in[5];
    const void* bp_user   = d_in[6];
    const void* Wp_item   = d_in[7];
    const void* bp_item   = d_in[8];
    const void* eps       = d_in[9];
    const void* We        = d_in[10];
    const void* be        = d_in[11];
    const void* W1        = d_in[12];
    const void* b1        = d_in[13];
    const void* W2        = d_in[14];
    const void* b2        = d_in[15];

    // Workspace layout (4B elements, 256-aligned).
    // Layer-1 agg outputs reuse h_u / h_i (dead after the layer-0 agg pass).
    float* ws   = (float*)d_ws;
    int*  flag  = (int*)d_ws;
    float* h_u  = ws + 256;             // 12.8M
    float* h_i  = h_u + 12800000;       //  6.4M
    float* h_u2 = h_i + 6400000;        // 12.8M
    float* h_i2 = h_u2 + 12800000;      //  6.4M
    int* rowptr_i = (int*)(h_i2 + 6400000);   // 100,001 (pad 100,096)
    int* cursor_i = rowptr_i + 100096;        // 100,000 (pad 100,096); also deg
    int2* perm_i  = (int2*)(cursor_i + 100096);  // 1M int2
    int* rowptr_u = (int*)(perm_i + 1000000); // 200,001 (pad 200,192)
    int* cursor_u = rowptr_u + 200192;        // 200,000 (pad 200,192)
    int2* perm_u  = (int2*)(cursor_u + 200192);  // 1M int2

    const int EG = (NEDGE + 255) / 256;

    detect_kernel<<<1, 64, 0, stream>>>(x_user, flag);

    // CSR build: both relations in single passes over the edge list.
    hipMemsetAsync(cursor_i, 0, N_ITEM * sizeof(int), stream);
    hipMemsetAsync(cursor_u, 0, N_USER * sizeof(int), stream);
    hist2_kernel<<<EG, 256, 0, stream>>>(src_idx, dst_idx, cursor_u, cursor_i, NEDGE);
    scan_kernel<<<2, 1024, 0, stream>>>(cursor_i, rowptr_i, N_ITEM,
                                        cursor_u, rowptr_u, N_USER);
    scatter2_kernel<<<EG, 256, 0, stream>>>(src_idx, dst_idx, cursor_u, cursor_i,
                                            perm_u, perm_i, NEDGE);

    // input projections
    proj_kernel<128><<<1024, 256, 0, stream>>>(x_user, Wp_user, bp_user, h_u, N_USER, flag);
    proj_kernel<64><<<1024, 256, 0, stream>>>(x_item, Wp_item, bp_item, h_i, N_ITEM, flag);

    // ---- layer 0 (no residual): aggs read (h_u,h_i) snapshot, write h_*2;
    //      MLPs run in-place on h_*2.
    agg_kernel<<<2048, 256, 0, stream>>>(h_u, h_i, rowptr_i, perm_i, edge_attr,
        We, 0 * 1024, be, 0 * 64, eps, 0, h_i2, N_ITEM, flag);
    agg_kernel<<<2048, 256, 0, stream>>>(h_i, h_u, rowptr_u, perm_u, edge_attr,
        We, 1 * 1024, be, 1 * 64, eps, 1, h_u2, N_USER, flag);
    mlp_kernel<0><<<1024, 256, 0, stream>>>(h_i2, nullptr,
        W1, b1, W2, b2, 0 * 4096, 0 * 64, h_i2, nullptr, 0, N_ITEM, flag);
    mlp_kernel<0><<<1024, 256, 0, stream>>>(h_u2, nullptr,
        W1, b1, W2, b2, 1 * 4096, 1 * 64, h_u2, nullptr, 0, N_USER, flag);

    // ---- layer 1 (residual): aggs read (h_u2,h_i2), write into dead h_i/h_u;
    //      MLPs add resid = h_*2 and store to d_out in the flagged dtype.
    agg_kernel<<<2048, 256, 0, stream>>>(h_u2, h_i2, rowptr_i, perm_i, edge_attr,
        We, 2 * 1024, be, 2 * 64, eps, 2, h_i, N_ITEM, flag);
    agg_kernel<<<2048, 256, 0, stream>>>(h_i2, h_u2, rowptr_u, perm_u, edge_attr,
        We, 3 * 1024, be, 3 * 64, eps, 3, h_u, N_USER, flag);
    mlp_kernel<1><<<1024, 256, 0, stream>>>(h_i, h_i2,
        W1, b1, W2, b2, 2 * 4096, 2 * 64, nullptr, d_out, (long)N_USER * HID, N_ITEM, flag);
    mlp_kernel<1><<<1024, 256, 0, stream>>>(h_u, h_u2,
        W1, b1, W2, b2, 3 * 4096, 3 * 64, nullptr, d_out, 0, N_USER, flag);
}

// Round 4
// 3254.327 us; speedup vs baseline: 2.0225x; 1.0504x over previous
//
#include <hip/hip_runtime.h>
#include <hip/hip_bf16.h>

typedef __hip_bfloat16 bf16;

#define N_USER 200000
#define N_ITEM 100000
#define NEDGE  1000000
#define HID    64

// ---------------------------------------------------------------------------
// Dtype-agnostic access: harness data may be fp32 or bf16 (detected at runtime
// each launch — no static state, graph-safe). Offsets are ELEMENT offsets.
// ---------------------------------------------------------------------------
__device__ __forceinline__ float bf2f(unsigned int u) {
    unsigned int x = u << 16;
    float f; __builtin_memcpy(&f, &x, 4); return f;
}
__device__ __forceinline__ float ldf(const void* p, long i, int isf32) {
    if (isf32) return ((const float*)p)[i];
    return bf2f(((const unsigned short*)p)[i]);
}
__device__ __forceinline__ void stf(void* p, long i, int isf32, float v) {
    if (isf32) ((float*)p)[i] = v;
    else       ((bf16*)p)[i] = (bf16)v;
}
// Load one edge_attr row (16 elems) vectorized: fp32 = 4x float4, bf16 = 2x int4.
__device__ __forceinline__ void load_row16(const void* ea, long e, int isf32, float* v) {
    if (isf32) {
        const float4* p = (const float4*)((const float*)ea + e * 16);
        float4 a = p[0], b = p[1], c = p[2], d = p[3];
        v[0]=a.x; v[1]=a.y; v[2]=a.z; v[3]=a.w;
        v[4]=b.x; v[5]=b.y; v[6]=b.z; v[7]=b.w;
        v[8]=c.x; v[9]=c.y; v[10]=c.z; v[11]=c.w;
        v[12]=d.x; v[13]=d.y; v[14]=d.z; v[15]=d.w;
    } else {
        const int4* q = (const int4*)((const unsigned short*)ea + e * 16);
        int4 s0 = q[0], s1 = q[1];
        unsigned int w;
        w=(unsigned)s0.x; v[0]=bf2f(w & 0xffff); v[1]=bf2f(w >> 16);
        w=(unsigned)s0.y; v[2]=bf2f(w & 0xffff); v[3]=bf2f(w >> 16);
        w=(unsigned)s0.z; v[4]=bf2f(w & 0xffff); v[5]=bf2f(w >> 16);
        w=(unsigned)s0.w; v[6]=bf2f(w & 0xffff); v[7]=bf2f(w >> 16);
        w=(unsigned)s1.x; v[8]=bf2f(w & 0xffff); v[9]=bf2f(w >> 16);
        w=(unsigned)s1.y; v[10]=bf2f(w & 0xffff); v[11]=bf2f(w >> 16);
        w=(unsigned)s1.z; v[12]=bf2f(w & 0xffff); v[13]=bf2f(w >> 16);
        w=(unsigned)s1.w; v[14]=bf2f(w & 0xffff); v[15]=bf2f(w >> 16);
    }
}

// fp32-vs-bf16 detector (R3-verified): fp32's interleaved mantissa halves hit
// biased exp >= 137 with p~0.46/word; true bf16 N(0,1) never does.
__global__ void detect_kernel(const void* __restrict__ x, int* __restrict__ flag) {
    const unsigned short* p = (const unsigned short*)x;
    int f = 0;
    for (int k = threadIdx.x; k < 512; k += 64) {
        int ex = (p[k] >> 7) & 0xFF;
        if (ex >= 137) f = 1;
    }
    unsigned long long b = __ballot(f != 0);
    if (threadIdx.x == 0) *flag = (b != 0ULL) ? 1 : 0;
}

// ---------------------------------------------------------------------------
// CSR build: fused dual histogram -> shuffle-scan (both arrays, 2 WGs) ->
// fused dual scatter. cursor doubles as the degree array.
// ---------------------------------------------------------------------------
__global__ __launch_bounds__(256) void hist2_kernel(
    const int* __restrict__ src, const int* __restrict__ dst,
    int* __restrict__ cnt_u, int* __restrict__ cnt_i, int E)
{
    int e = blockIdx.x * 256 + threadIdx.x;
    if (e < E) {
        atomicAdd(&cnt_u[src[e]], 1);
        atomicAdd(&cnt_i[dst[e]], 1);
    }
}

__device__ __forceinline__ int wave_incl_scan(int v, int lane) {
#pragma unroll
    for (int off = 1; off < 64; off <<= 1) {
        int t = __shfl_up(v, off, 64);
        if (lane >= off) v += t;
    }
    return v;
}

// block 0 scans the item degrees, block 1 the user degrees.
__global__ __launch_bounds__(1024) void scan_kernel(
    int* __restrict__ deg_i, int* __restrict__ rp_i, int Ni,
    int* __restrict__ deg_u, int* __restrict__ rp_u, int Nu)
{
    __shared__ int swsum[16];
    __shared__ int s_carry;
    int* deg    = (blockIdx.x == 0) ? deg_i : deg_u;
    int* rowptr = (blockIdx.x == 0) ? rp_i  : rp_u;
    int N       = (blockIdx.x == 0) ? Ni    : Nu;
    int tid = threadIdx.x, lane = tid & 63, wid = tid >> 6;
    if (tid == 0) s_carry = 0;
    int grand = 0;
    for (int base = 0; base < N; base += 8192) {
        int i0 = base + tid * 8;
        int v[8]; int tot = 0;
#pragma unroll
        for (int k = 0; k < 8; k++) { int i = i0 + k; v[k] = (i < N) ? deg[i] : 0; tot += v[k]; }
        int incl = wave_incl_scan(tot, lane);
        if (lane == 63) swsum[wid] = incl;
        __syncthreads();                       // A: swsum ready, s_carry stable
        int carry = s_carry;
        int wbase = 0;
        for (int jw = 0; jw < wid; jw++) wbase += swsum[jw];
        int exc = carry + wbase + incl - tot;
#pragma unroll
        for (int k = 0; k < 8; k++) {
            int i = i0 + k;
            if (i < N) { rowptr[i] = exc; deg[i] = exc; }   // deg becomes cursor
            exc += v[k];
        }
        __syncthreads();                       // B: all reads of s_carry/swsum done
        if (tid == 1023) { s_carry = exc; grand = exc; }    // exc = carry + chunk total
    }
    if (tid == 1023) rowptr[N] = grand;
}

__global__ __launch_bounds__(256) void scatter2_kernel(
    const int* __restrict__ src, const int* __restrict__ dst,
    int* __restrict__ cur_u, int* __restrict__ cur_i,
    int2* __restrict__ perm_u, int2* __restrict__ perm_i, int E)
{
    int e = blockIdx.x * 256 + threadIdx.x;
    if (e >= E) return;
    int s = src[e], d = dst[e];
    int pu = atomicAdd(&cur_u[s], 1);
    perm_u[pu] = make_int2(e, d);
    int pi = atomicAdd(&cur_i[d], 1);
    perm_i[pi] = make_int2(e, s);
}

// ---------------------------------------------------------------------------
// Input projection (grid-stride): out[n,c] = relu(x[n,:]@W[:,c] + b[c]).
// Proven-fast template (never appears in top-5).
// ---------------------------------------------------------------------------
template<int K>
__global__ __launch_bounds__(256) void proj_kernel(
    const void* __restrict__ x, const void* __restrict__ W,
    const void* __restrict__ b, float* __restrict__ out, int N,
    const int* __restrict__ flagp)
{
    __shared__ float Ws[K * 64];
    __shared__ float xs[4][K];
    int isf32 = *flagp;
    int tid = threadIdx.x;
    for (int i = tid; i < K * 64; i += 256) Ws[i] = ldf(W, i, isf32);
    int r = tid >> 6, c = tid & 63;
    float bc = ldf(b, c, isf32);
    for (int row0 = blockIdx.x * 4; row0 < N; row0 += gridDim.x * 4) {
        __syncthreads();   // WAR on xs (and Ws staging, first iter)
        for (int i = tid; i < 4 * K; i += 256) {
            int rr = i / K, k = i - rr * K;
            int row = row0 + rr;
            xs[rr][k] = (row < N) ? ldf(x, (long)row * K + k, isf32) : 0.f;
        }
        __syncthreads();
        int row = row0 + r;
        float acc = bc;
#pragma unroll
        for (int k = 0; k < K; k++) acc = fmaf(xs[r][k], Ws[k * 64 + c], acc);
        if (row < N) out[(long)row * 64 + c] = fmaxf(acc, 0.f);
    }
}

// ---------------------------------------------------------------------------
// Phase A — fused edge aggregation + W1 (barrier-free):
//   v[c]   = (1+eps)*h_dst[n,c] + sum_j relu(h_src[src_j][c] + ea@We[:,c] + be[c])
//   t[n,c] = relu(b1[c] + sum_k v[k]*W1[k][c])     via 64x __shfl (v is
//            one-elem-per-lane in the wave; no vs/ts LDS, no loop barriers)
// One wave per node; waves fully independent. LDS = Wes 4K + W1s 16K +
// biases = 20.99 KB -> 7 blocks/CU = 28 waves/CU. __launch_bounds__(256,4)
// = the R0/R3-proven 64-VGPR no-spill regime for this gather loop ((256,8)
// forced VGPR=32 and spilled a0..a3 -> 3.7 GB scratch traffic, R1).
// ---------------------------------------------------------------------------
__global__ __launch_bounds__(256, 4) void agg_w1_kernel(
    const float* __restrict__ h_src, const float* __restrict__ h_dst,
    const int* __restrict__ rowptr, const int2* __restrict__ perm,
    const void* __restrict__ ea,
    const void* __restrict__ We, long weoff, const void* __restrict__ be, long beoff,
    const void* __restrict__ W1, long w1off, const void* __restrict__ b1, long b1off,
    const void* __restrict__ eps, int conv,
    float* __restrict__ t_out, int N, const int* __restrict__ flagp)
{
    __shared__ float Wes[16 * 64];
    __shared__ float W1s[64 * 64];
    __shared__ float bes[64], b1s[64];
    int isf32 = *flagp;
    int tid = threadIdx.x;
    for (int i = tid; i < 1024; i += 256) Wes[i] = ldf(We, weoff + i, isf32);
    for (int i = tid; i < 4096; i += 256) W1s[i] = ldf(W1, w1off + i, isf32);
    if (tid < 64) {
        bes[tid] = ldf(be, beoff + tid, isf32);
        b1s[tid] = ldf(b1, b1off + tid, isf32);
    }
    __syncthreads();
    float eps1 = 1.f + ldf(eps, conv, isf32);
    int w = tid >> 6, c = tid & 63;
    float bec = bes[c];
    float b1c = b1s[c];

    for (int n = blockIdx.x * 4 + w; n < N; n += gridDim.x * 4) {
        float hv = h_dst[(long)n * 64 + c];
        float acc = 0.f;
        int jb = rowptr[n], je = rowptr[n + 1];
        int j = jb;
        for (; j + 4 <= je; j += 4) {
            int2 p0 = perm[j], p1 = perm[j+1], p2 = perm[j+2], p3 = perm[j+3];
            float a0[16], a1[16], a2[16], a3[16];
            load_row16(ea, p0.x, isf32, a0);
            load_row16(ea, p1.x, isf32, a1);
            load_row16(ea, p2.x, isf32, a2);
            load_row16(ea, p3.x, isf32, a3);
            float h0 = h_src[(long)p0.y * 64 + c];
            float h1 = h_src[(long)p1.y * 64 + c];
            float h2 = h_src[(long)p2.y * 64 + c];
            float h3 = h_src[(long)p3.y * 64 + c];
            float m0 = bec, m1 = bec, m2 = bec, m3 = bec;
#pragma unroll
            for (int k = 0; k < 16; k++) {
                float wv = Wes[k * 64 + c];
                m0 = fmaf(a0[k], wv, m0); m1 = fmaf(a1[k], wv, m1);
                m2 = fmaf(a2[k], wv, m2); m3 = fmaf(a3[k], wv, m3);
            }
            acc += fmaxf(m0 + h0, 0.f); acc += fmaxf(m1 + h1, 0.f);
            acc += fmaxf(m2 + h2, 0.f); acc += fmaxf(m3 + h3, 0.f);
        }
        for (; j < je; j++) {
            int2 p0 = perm[j];
            float a0[16];
            load_row16(ea, p0.x, isf32, a0);
            float h0 = h_src[(long)p0.y * 64 + c];
            float m0 = bec;
#pragma unroll
            for (int k = 0; k < 16; k++) m0 = fmaf(a0[k], Wes[k * 64 + c], m0);
            acc += fmaxf(m0 + h0, 0.f);
        }
        float v = eps1 * hv + acc;
        // t[c] = relu(b1[c] + sum_k v[k] * W1[k][c]) — v[k] via wave shfl.
        float tacc = b1c;
#pragma unroll
        for (int k = 0; k < 64; k++) {
            float vk = __shfl(v, k, 64);
            tacc = fmaf(vk, W1s[k * 64 + c], tacc);
        }
        t_out[(long)n * 64 + c] = fmaxf(tacc, 0.f);
    }
}

// ---------------------------------------------------------------------------
// Phase B — W2 + optional residual + dtype store. Literal clone of the
// proven-fast proj_kernel pattern (K=64). In-place safe: a block writes
// exactly the rows it staged, rows partitioned disjointly across blocks.
// ---------------------------------------------------------------------------
template<int RESID>
__global__ __launch_bounds__(256) void w2_kernel(
    const float* __restrict__ t, const float* __restrict__ resid,
    const void* __restrict__ W2, const void* __restrict__ b2, long woff, long boff,
    float* __restrict__ outf, void* __restrict__ outv, long outoff,
    int N, const int* __restrict__ flagp)
{
    __shared__ float Ws[4096];
    __shared__ float xs[4][64];
    int isf32 = *flagp;
    int tid = threadIdx.x;
    for (int i = tid; i < 4096; i += 256) Ws[i] = ldf(W2, woff + i, isf32);
    int r = tid >> 6, c = tid & 63;
    float bc = ldf(b2, boff + c, isf32);
    for (int row0 = blockIdx.x * 4; row0 < N; row0 += gridDim.x * 4) {
        __syncthreads();   // WAR on xs (and Ws staging, first iter)
        {   // 4 rows x 64 = 256 = blockDim: single staging statement
            int rr = tid >> 6, k = tid & 63;
            int row = row0 + rr;
            xs[rr][k] = (row < N) ? t[(long)row * 64 + k] : 0.f;
        }
        __syncthreads();
        int row = row0 + r;
        float acc = bc;
#pragma unroll
        for (int k = 0; k < 64; k++) acc = fmaf(xs[r][k], Ws[k * 64 + c], acc);
        if (row < N) {
            float o = fmaxf(acc, 0.f);
            if (RESID) o += resid[(long)row * 64 + c];
            long base = (long)row * 64 + c;
            if (outv) stf(outv, outoff + base, isf32, o);
            else      outf[base] = o;
        }
    }
}

extern "C" void kernel_launch(void* const* d_in, const int* in_sizes, int n_in,
                              void* d_out, int out_size, void* d_ws, size_t ws_size,
                              hipStream_t stream)
{
    const void* x_user    = d_in[0];
    const void* x_item    = d_in[1];
    const void* edge_attr = d_in[2];
    const int*  src_idx   = (const int*)d_in[3];
    const int*  dst_idx   = (const int*)d_in[4];
    const void* Wp_user   = d_in[5];
    const void* bp_user   = d_in[6];
    const void* Wp_item   = d_in[7];
    const void* bp_item   = d_in[8];
    const void* eps       = d_in[9];
    const void* We        = d_in[10];
    const void* be        = d_in[11];
    const void* W1        = d_in[12];
    const void* b1        = d_in[13];
    const void* W2        = d_in[14];
    const void* b2        = d_in[15];

    // Workspace layout (4B elements, 256-aligned) — unchanged footprint.
    // t-buffers alias: layer 0 writes t into h_*2 (then w2 runs in-place);
    // layer 1 writes t into dead h_i / h_u.
    float* ws   = (float*)d_ws;
    int*  flag  = (int*)d_ws;
    float* h_u  = ws + 256;             // 12.8M
    float* h_i  = h_u + 12800000;       //  6.4M
    float* h_u2 = h_i + 6400000;        // 12.8M
    float* h_i2 = h_u2 + 12800000;      //  6.4M
    int* rowptr_i = (int*)(h_i2 + 6400000);   // 100,001 (pad 100,096)
    int* cursor_i = rowptr_i + 100096;        // 100,000 (pad 100,096); also deg
    int2* perm_i  = (int2*)(cursor_i + 100096);  // 1M int2
    int* rowptr_u = (int*)(perm_i + 1000000); // 200,001 (pad 200,192)
    int* cursor_u = rowptr_u + 200192;        // 200,000 (pad 200,192)
    int2* perm_u  = (int2*)(cursor_u + 200192);  // 1M int2

    const int EG = (NEDGE + 255) / 256;

    detect_kernel<<<1, 64, 0, stream>>>(x_user, flag);

    // CSR build: both relations in single passes over the edge list.
    hipMemsetAsync(cursor_i, 0, N_ITEM * sizeof(int), stream);
    hipMemsetAsync(cursor_u, 0, N_USER * sizeof(int), stream);
    hist2_kernel<<<EG, 256, 0, stream>>>(src_idx, dst_idx, cursor_u, cursor_i, NEDGE);
    scan_kernel<<<2, 1024, 0, stream>>>(cursor_i, rowptr_i, N_ITEM,
                                        cursor_u, rowptr_u, N_USER);
    scatter2_kernel<<<EG, 256, 0, stream>>>(src_idx, dst_idx, cursor_u, cursor_i,
                                            perm_u, perm_i, NEDGE);

    // input projections
    proj_kernel<128><<<1024, 256, 0, stream>>>(x_user, Wp_user, bp_user, h_u, N_USER, flag);
    proj_kernel<64><<<1024, 256, 0, stream>>>(x_item, Wp_item, bp_item, h_i, N_ITEM, flag);

    // ---- layer 0 (no residual): agg+W1 -> t in h_*2; w2 in-place on h_*2.
    agg_w1_kernel<<<2048, 256, 0, stream>>>(h_u, h_i, rowptr_i, perm_i, edge_attr,
        We, 0 * 1024, be, 0 * 64, W1, 0 * 4096, b1, 0 * 64,
        eps, 0, h_i2, N_ITEM, flag);
    agg_w1_kernel<<<2048, 256, 0, stream>>>(h_i, h_u, rowptr_u, perm_u, edge_attr,
        We, 1 * 1024, be, 1 * 64, W1, 1 * 4096, b1, 1 * 64,
        eps, 1, h_u2, N_USER, flag);
    w2_kernel<0><<<1024, 256, 0, stream>>>(h_i2, nullptr,
        W2, b2, 0 * 4096, 0 * 64, h_i2, nullptr, 0, N_ITEM, flag);
    w2_kernel<0><<<1024, 256, 0, stream>>>(h_u2, nullptr,
        W2, b2, 1 * 4096, 1 * 64, h_u2, nullptr, 0, N_USER, flag);

    // ---- layer 1 (residual): agg+W1 reads h_*2, t into dead h_i / h_u;
    //      w2 adds resid = h_*2 and stores to d_out in the flagged dtype.
    agg_w1_kernel<<<2048, 256, 0, stream>>>(h_u2, h_i2, rowptr_i, perm_i, edge_attr,
        We, 2 * 1024, be, 2 * 64, W1, 2 * 4096, b1, 2 * 64,
        eps, 2, h_i, N_ITEM, flag);
    agg_w1_kernel<<<2048, 256, 0, stream>>>(h_i2, h_u2, rowptr_u, perm_u, edge_attr,
        We, 3 * 1024, be, 3 * 64, W1, 3 * 4096, b1, 3 * 64,
        eps, 3, h_u, N_USER, flag);
    w2_kernel<1><<<1024, 256, 0, stream>>>(h_i, h_i2,
        W2, b2, 2 * 4096, 2 * 64, nullptr, d_out, (long)N_USER * HID, N_ITEM, flag);
    w2_kernel<1><<<1024, 256, 0, stream>>>(h_u, h_u2,
        W2, b2, 3 * 4096, 3 * 64, nullptr, d_out, 0, N_USER, flag);
}

// Round 5
// 2363.240 us; speedup vs baseline: 2.7851x; 1.3771x over previous
//
#include <hip/hip_runtime.h>
#include <hip/hip_bf16.h>

typedef __hip_bfloat16 bf16;

#define N_USER 200000
#define N_ITEM 100000
#define NEDGE  1000000
#define HID    64

// ---------------------------------------------------------------------------
// Dtype-agnostic access: harness data may be fp32 or bf16 (detected at runtime
// each launch — no static state, graph-safe). Offsets are ELEMENT offsets.
// ---------------------------------------------------------------------------
__device__ __forceinline__ float bf2f(unsigned int u) {
    unsigned int x = u << 16;
    float f; __builtin_memcpy(&f, &x, 4); return f;
}
__device__ __forceinline__ float ldf(const void* p, long i, int isf32) {
    if (isf32) return ((const float*)p)[i];
    return bf2f(((const unsigned short*)p)[i]);
}
__device__ __forceinline__ void stf(void* p, long i, int isf32, float v) {
    if (isf32) ((float*)p)[i] = v;
    else       ((bf16*)p)[i] = (bf16)v;
}
// Load one edge_attr row (16 elems) vectorized: fp32 = 4x float4, bf16 = 2x int4.
__device__ __forceinline__ void load_row16(const void* ea, long e, int isf32, float* v) {
    if (isf32) {
        const float4* p = (const float4*)((const float*)ea + e * 16);
        float4 a = p[0], b = p[1], c = p[2], d = p[3];
        v[0]=a.x; v[1]=a.y; v[2]=a.z; v[3]=a.w;
        v[4]=b.x; v[5]=b.y; v[6]=b.z; v[7]=b.w;
        v[8]=c.x; v[9]=c.y; v[10]=c.z; v[11]=c.w;
        v[12]=d.x; v[13]=d.y; v[14]=d.z; v[15]=d.w;
    } else {
        const int4* q = (const int4*)((const unsigned short*)ea + e * 16);
        int4 s0 = q[0], s1 = q[1];
        unsigned int w;
        w=(unsigned)s0.x; v[0]=bf2f(w & 0xffff); v[1]=bf2f(w >> 16);
        w=(unsigned)s0.y; v[2]=bf2f(w & 0xffff); v[3]=bf2f(w >> 16);
        w=(unsigned)s0.z; v[4]=bf2f(w & 0xffff); v[5]=bf2f(w >> 16);
        w=(unsigned)s0.w; v[6]=bf2f(w & 0xffff); v[7]=bf2f(w >> 16);
        w=(unsigned)s1.x; v[8]=bf2f(w & 0xffff); v[9]=bf2f(w >> 16);
        w=(unsigned)s1.y; v[10]=bf2f(w & 0xffff); v[11]=bf2f(w >> 16);
        w=(unsigned)s1.z; v[12]=bf2f(w & 0xffff); v[13]=bf2f(w >> 16);
        w=(unsigned)s1.w; v[14]=bf2f(w & 0xffff); v[15]=bf2f(w >> 16);
    }
}

// fp32-vs-bf16 detector (R3-verified): fp32's interleaved mantissa halves hit
// biased exp >= 137 with p~0.46/word; true bf16 N(0,1) never does.
__global__ void detect_kernel(const void* __restrict__ x, int* __restrict__ flag) {
    const unsigned short* p = (const unsigned short*)x;
    int f = 0;
    for (int k = threadIdx.x; k < 512; k += 64) {
        int ex = (p[k] >> 7) & 0xFF;
        if (ex >= 137) f = 1;
    }
    unsigned long long b = __ballot(f != 0);
    if (threadIdx.x == 0) *flag = (b != 0ULL) ? 1 : 0;
}

// ---------------------------------------------------------------------------
// CSR build: fused dual histogram -> shuffle-scan (both arrays, 2 WGs) ->
// fused dual scatter. cursor doubles as the degree array.
// ---------------------------------------------------------------------------
__global__ __launch_bounds__(256) void hist2_kernel(
    const int* __restrict__ src, const int* __restrict__ dst,
    int* __restrict__ cnt_u, int* __restrict__ cnt_i, int E)
{
    int e = blockIdx.x * 256 + threadIdx.x;
    if (e < E) {
        atomicAdd(&cnt_u[src[e]], 1);
        atomicAdd(&cnt_i[dst[e]], 1);
    }
}

__device__ __forceinline__ int wave_incl_scan(int v, int lane) {
#pragma unroll
    for (int off = 1; off < 64; off <<= 1) {
        int t = __shfl_up(v, off, 64);
        if (lane >= off) v += t;
    }
    return v;
}

// block 0 scans the item degrees, block 1 the user degrees.
__global__ __launch_bounds__(1024) void scan_kernel(
    int* __restrict__ deg_i, int* __restrict__ rp_i, int Ni,
    int* __restrict__ deg_u, int* __restrict__ rp_u, int Nu)
{
    __shared__ int swsum[16];
    __shared__ int s_carry;
    int* deg    = (blockIdx.x == 0) ? deg_i : deg_u;
    int* rowptr = (blockIdx.x == 0) ? rp_i  : rp_u;
    int N       = (blockIdx.x == 0) ? Ni    : Nu;
    int tid = threadIdx.x, lane = tid & 63, wid = tid >> 6;
    if (tid == 0) s_carry = 0;
    int grand = 0;
    for (int base = 0; base < N; base += 8192) {
        int i0 = base + tid * 8;
        int v[8]; int tot = 0;
#pragma unroll
        for (int k = 0; k < 8; k++) { int i = i0 + k; v[k] = (i < N) ? deg[i] : 0; tot += v[k]; }
        int incl = wave_incl_scan(tot, lane);
        if (lane == 63) swsum[wid] = incl;
        __syncthreads();                       // A: swsum ready, s_carry stable
        int carry = s_carry;
        int wbase = 0;
        for (int jw = 0; jw < wid; jw++) wbase += swsum[jw];
        int exc = carry + wbase + incl - tot;
#pragma unroll
        for (int k = 0; k < 8; k++) {
            int i = i0 + k;
            if (i < N) { rowptr[i] = exc; deg[i] = exc; }   // deg becomes cursor
            exc += v[k];
        }
        __syncthreads();                       // B: all reads of s_carry/swsum done
        if (tid == 1023) { s_carry = exc; grand = exc; }    // exc = carry + chunk total
    }
    if (tid == 1023) rowptr[N] = grand;
}

__global__ __launch_bounds__(256) void scatter2_kernel(
    const int* __restrict__ src, const int* __restrict__ dst,
    int* __restrict__ cur_u, int* __restrict__ cur_i,
    int2* __restrict__ perm_u, int2* __restrict__ perm_i, int E)
{
    int e = blockIdx.x * 256 + threadIdx.x;
    if (e >= E) return;
    int s = src[e], d = dst[e];
    int pu = atomicAdd(&cur_u[s], 1);
    perm_u[pu] = make_int2(e, d);
    int pi = atomicAdd(&cur_i[d], 1);
    perm_i[pi] = make_int2(e, s);
}

// ---------------------------------------------------------------------------
// Input projection (grid-stride): out[n,c] = relu(x[n,:]@W[:,c] + b[c]).
// Proven-fast template (never appears in top-5).
// ---------------------------------------------------------------------------
template<int K>
__global__ __launch_bounds__(256) void proj_kernel(
    const void* __restrict__ x, const void* __restrict__ W,
    const void* __restrict__ b, float* __restrict__ out, int N,
    const int* __restrict__ flagp)
{
    __shared__ float Ws[K * 64];
    __shared__ float xs[4][K];
    int isf32 = *flagp;
    int tid = threadIdx.x;
    for (int i = tid; i < K * 64; i += 256) Ws[i] = ldf(W, i, isf32);
    int r = tid >> 6, c = tid & 63;
    float bc = ldf(b, c, isf32);
    for (int row0 = blockIdx.x * 4; row0 < N; row0 += gridDim.x * 4) {
        __syncthreads();   // WAR on xs (and Ws staging, first iter)
        for (int i = tid; i < 4 * K; i += 256) {
            int rr = i / K, k = i - rr * K;
            int row = row0 + rr;
            xs[rr][k] = (row < N) ? ldf(x, (long)row * K + k, isf32) : 0.f;
        }
        __syncthreads();
        int row = row0 + r;
        float acc = bc;
#pragma unroll
        for (int k = 0; k < K; k++) acc = fmaf(xs[r][k], Ws[k * 64 + c], acc);
        if (row < N) out[(long)row * 64 + c] = fmaxf(acc, 0.f);
    }
}

// ---------------------------------------------------------------------------
// Phase A — edge aggregation only (R3-VERBATIM; proven ~95-130 us, no spill):
//   agg[n,c] = (1+eps)*h_dst[n,c] + sum_{j in CSR[n]} relu(h_src[src_j][c]
//              + ea[e_j]@We[:,c] + be[c])
// One wave per node, zero barriers in the loop. LDS 4.6 KB. Do NOT graft
// extra per-node tails here: R4's shfl-W1 tail changed regalloc and spilled
// the a0..a3 arrays in the EDGE loop (578 us, edge-proportional scratch
// traffic). __launch_bounds__(256,4) = proven 64-VGPR no-spill regime.
// ---------------------------------------------------------------------------
__global__ __launch_bounds__(256, 4) void agg_kernel(
    const float* __restrict__ h_src, const float* __restrict__ h_dst,
    const int* __restrict__ rowptr, const int2* __restrict__ perm,
    const void* __restrict__ ea,
    const void* __restrict__ We, long weoff, const void* __restrict__ be, long beoff,
    const void* __restrict__ eps, int conv,
    float* __restrict__ agg, int N, const int* __restrict__ flagp)
{
    __shared__ float Wes[16 * 64];
    __shared__ float bes[64];
    int isf32 = *flagp;
    int tid = threadIdx.x;
    for (int i = tid; i < 1024; i += 256) Wes[i] = ldf(We, weoff + i, isf32);
    if (tid < 64) bes[tid] = ldf(be, beoff + tid, isf32);
    __syncthreads();
    float eps1 = 1.f + ldf(eps, conv, isf32);
    int w = tid >> 6, c = tid & 63;
    float bec = bes[c];

    for (int n = blockIdx.x * 4 + w; n < N; n += gridDim.x * 4) {
        float hv = h_dst[(long)n * 64 + c];
        float acc = 0.f;
        int jb = rowptr[n], je = rowptr[n + 1];
        int j = jb;
        for (; j + 4 <= je; j += 4) {
            int2 p0 = perm[j], p1 = perm[j+1], p2 = perm[j+2], p3 = perm[j+3];
            float a0[16], a1[16], a2[16], a3[16];
            load_row16(ea, p0.x, isf32, a0);
            load_row16(ea, p1.x, isf32, a1);
            load_row16(ea, p2.x, isf32, a2);
            load_row16(ea, p3.x, isf32, a3);
            float h0 = h_src[(long)p0.y * 64 + c];
            float h1 = h_src[(long)p1.y * 64 + c];
            float h2 = h_src[(long)p2.y * 64 + c];
            float h3 = h_src[(long)p3.y * 64 + c];
            float m0 = bec, m1 = bec, m2 = bec, m3 = bec;
#pragma unroll
            for (int k = 0; k < 16; k++) {
                float wv = Wes[k * 64 + c];
                m0 = fmaf(a0[k], wv, m0); m1 = fmaf(a1[k], wv, m1);
                m2 = fmaf(a2[k], wv, m2); m3 = fmaf(a3[k], wv, m3);
            }
            acc += fmaxf(m0 + h0, 0.f); acc += fmaxf(m1 + h1, 0.f);
            acc += fmaxf(m2 + h2, 0.f); acc += fmaxf(m3 + h3, 0.f);
        }
        for (; j < je; j++) {
            int2 p0 = perm[j];
            float a0[16];
            load_row16(ea, p0.x, isf32, a0);
            float h0 = h_src[(long)p0.y * 64 + c];
            float m0 = bec;
#pragma unroll
            for (int k = 0; k < 16; k++) m0 = fmaf(a0[k], Wes[k * 64 + c], m0);
            acc += fmaxf(m0 + h0, 0.f);
        }
        agg[(long)n * 64 + c] = eps1 * hv + acc;
    }
}

// ---------------------------------------------------------------------------
// Phase B1 — W1 matvec: v[n,:] -> t[n,c] = relu(b1[c] + v@W1[:,c]).
// proj/w2-clone (the proven-fast single-weight 16.5 KB class), fp32 input,
// IN-PLACE safe (each block writes exactly the rows it staged).
// Grid 2048 (vs w2's 1024): deliberate A/B on grid size for this class.
// ---------------------------------------------------------------------------
__global__ __launch_bounds__(256) void w1_kernel(
    const float* __restrict__ v,
    const void* __restrict__ W1, const void* __restrict__ b1, long woff, long boff,
    float* __restrict__ t, int N, const int* __restrict__ flagp)
{
    __shared__ float Ws[4096];
    __shared__ float xs[4][64];
    int isf32 = *flagp;
    int tid = threadIdx.x;
    for (int i = tid; i < 4096; i += 256) Ws[i] = ldf(W1, woff + i, isf32);
    int r = tid >> 6, c = tid & 63;
    float bc = ldf(b1, boff + c, isf32);
    for (int row0 = blockIdx.x * 4; row0 < N; row0 += gridDim.x * 4) {
        __syncthreads();   // WAR on xs (and Ws staging, first iter)
        {
            int rr = tid >> 6, k = tid & 63;
            int row = row0 + rr;
            xs[rr][k] = (row < N) ? v[(long)row * 64 + k] : 0.f;
        }
        __syncthreads();
        int row = row0 + r;
        float acc = bc;
#pragma unroll
        for (int k = 0; k < 64; k++) acc = fmaf(xs[r][k], Ws[k * 64 + c], acc);
        if (row < N) t[(long)row * 64 + c] = fmaxf(acc, 0.f);
    }
}

// ---------------------------------------------------------------------------
// Phase B2 — W2 + optional residual + dtype store (unchanged from R4;
// proven ~150 us class). In-place safe.
// ---------------------------------------------------------------------------
template<int RESID>
__global__ __launch_bounds__(256) void w2_kernel(
    const float* __restrict__ t, const float* __restrict__ resid,
    const void* __restrict__ W2, const void* __restrict__ b2, long woff, long boff,
    float* __restrict__ outf, void* __restrict__ outv, long outoff,
    int N, const int* __restrict__ flagp)
{
    __shared__ float Ws[4096];
    __shared__ float xs[4][64];
    int isf32 = *flagp;
    int tid = threadIdx.x;
    for (int i = tid; i < 4096; i += 256) Ws[i] = ldf(W2, woff + i, isf32);
    int r = tid >> 6, c = tid & 63;
    float bc = ldf(b2, boff + c, isf32);
    for (int row0 = blockIdx.x * 4; row0 < N; row0 += gridDim.x * 4) {
        __syncthreads();   // WAR on xs (and Ws staging, first iter)
        {
            int rr = tid >> 6, k = tid & 63;
            int row = row0 + rr;
            xs[rr][k] = (row < N) ? t[(long)row * 64 + k] : 0.f;
        }
        __syncthreads();
        int row = row0 + r;
        float acc = bc;
#pragma unroll
        for (int k = 0; k < 64; k++) acc = fmaf(xs[r][k], Ws[k * 64 + c], acc);
        if (row < N) {
            float o = fmaxf(acc, 0.f);
            if (RESID) o += resid[(long)row * 64 + c];
            long base = (long)row * 64 + c;
            if (outv) stf(outv, outoff + base, isf32, o);
            else      outf[base] = o;
        }
    }
}

extern "C" void kernel_launch(void* const* d_in, const int* in_sizes, int n_in,
                              void* d_out, int out_size, void* d_ws, size_t ws_size,
                              hipStream_t stream)
{
    const void* x_user    = d_in[0];
    const void* x_item    = d_in[1];
    const void* edge_attr = d_in[2];
    const int*  src_idx   = (const int*)d_in[3];
    const int*  dst_idx   = (const int*)d_in[4];
    const void* Wp_user   = d_in[5];
    const void* bp_user   = d_in[6];
    const void* Wp_item   = d_in[7];
    const void* bp_item   = d_in[8];
    const void* eps       = d_in[9];
    const void* We        = d_in[10];
    const void* be        = d_in[11];
    const void* W1        = d_in[12];
    const void* b1        = d_in[13];
    const void* W2        = d_in[14];
    const void* b2        = d_in[15];

    // Workspace layout (4B elements, 256-aligned) — unchanged footprint.
    // All MLP stages run in-place: layer 0 pipelines agg->w1->w2 inside h_*2;
    // layer 1 uses dead h_i / h_u for agg->w1, w2 reads them + resid h_*2.
    float* ws   = (float*)d_ws;
    int*  flag  = (int*)d_ws;
    float* h_u  = ws + 256;             // 12.8M
    float* h_i  = h_u + 12800000;       //  6.4M
    float* h_u2 = h_i + 6400000;        // 12.8M
    float* h_i2 = h_u2 + 12800000;      //  6.4M
    int* rowptr_i = (int*)(h_i2 + 6400000);   // 100,001 (pad 100,096)
    int* cursor_i = rowptr_i + 100096;        // 100,000 (pad 100,096); also deg
    int2* perm_i  = (int2*)(cursor_i + 100096);  // 1M int2
    int* rowptr_u = (int*)(perm_i + 1000000); // 200,001 (pad 200,192)
    int* cursor_u = rowptr_u + 200192;        // 200,000 (pad 200,192)
    int2* perm_u  = (int2*)(cursor_u + 200192);  // 1M int2

    const int EG = (NEDGE + 255) / 256;

    detect_kernel<<<1, 64, 0, stream>>>(x_user, flag);

    // CSR build: both relations in single passes over the edge list.
    hipMemsetAsync(cursor_i, 0, N_ITEM * sizeof(int), stream);
    hipMemsetAsync(cursor_u, 0, N_USER * sizeof(int), stream);
    hist2_kernel<<<EG, 256, 0, stream>>>(src_idx, dst_idx, cursor_u, cursor_i, NEDGE);
    scan_kernel<<<2, 1024, 0, stream>>>(cursor_i, rowptr_i, N_ITEM,
                                        cursor_u, rowptr_u, N_USER);
    scatter2_kernel<<<EG, 256, 0, stream>>>(src_idx, dst_idx, cursor_u, cursor_i,
                                            perm_u, perm_i, NEDGE);

    // input projections
    proj_kernel<128><<<1024, 256, 0, stream>>>(x_user, Wp_user, bp_user, h_u, N_USER, flag);
    proj_kernel<64><<<1024, 256, 0, stream>>>(x_item, Wp_item, bp_item, h_i, N_ITEM, flag);

    // ---- layer 0 (no residual): agg -> v in h_*2; w1 in-place; w2 in-place.
    agg_kernel<<<2048, 256, 0, stream>>>(h_u, h_i, rowptr_i, perm_i, edge_attr,
        We, 0 * 1024, be, 0 * 64, eps, 0, h_i2, N_ITEM, flag);
    agg_kernel<<<2048, 256, 0, stream>>>(h_i, h_u, rowptr_u, perm_u, edge_attr,
        We, 1 * 1024, be, 1 * 64, eps, 1, h_u2, N_USER, flag);
    w1_kernel<<<2048, 256, 0, stream>>>(h_i2, W1, b1, 0 * 4096, 0 * 64, h_i2, N_ITEM, flag);
    w1_kernel<<<2048, 256, 0, stream>>>(h_u2, W1, b1, 1 * 4096, 1 * 64, h_u2, N_USER, flag);
    w2_kernel<0><<<1024, 256, 0, stream>>>(h_i2, nullptr,
        W2, b2, 0 * 4096, 0 * 64, h_i2, nullptr, 0, N_ITEM, flag);
    w2_kernel<0><<<1024, 256, 0, stream>>>(h_u2, nullptr,
        W2, b2, 1 * 4096, 1 * 64, h_u2, nullptr, 0, N_USER, flag);

    // ---- layer 1 (residual): agg reads h_*2 -> v in dead h_i / h_u;
    //      w1 in-place; w2 adds resid = h_*2, stores to d_out (flagged dtype).
    agg_kernel<<<2048, 256, 0, stream>>>(h_u2, h_i2, rowptr_i, perm_i, edge_attr,
        We, 2 * 1024, be, 2 * 64, eps, 2, h_i, N_ITEM, flag);
    agg_kernel<<<2048, 256, 0, stream>>>(h_i2, h_u2, rowptr_u, perm_u, edge_attr,
        We, 3 * 1024, be, 3 * 64, eps, 3, h_u, N_USER, flag);
    w1_kernel<<<2048, 256, 0, stream>>>(h_i, W1, b1, 2 * 4096, 2 * 64, h_i, N_ITEM, flag);
    w1_kernel<<<2048, 256, 0, stream>>>(h_u, W1, b1, 3 * 4096, 3 * 64, h_u, N_USER, flag);
    w2_kernel<1><<<1024, 256, 0, stream>>>(h_i, h_i2,
        W2, b2, 2 * 4096, 2 * 64, nullptr, d_out, (long)N_USER * HID, N_ITEM, flag);
    w2_kernel<1><<<1024, 256, 0, stream>>>(h_u, h_u2,
        W2, b2, 3 * 4096, 3 * 64, nullptr, d_out, 0, N_USER, flag);
}

// Round 6
// 2126.926 us; speedup vs baseline: 3.0946x; 1.1111x over previous
//
#include <hip/hip_runtime.h>
#include <hip/hip_bf16.h>

typedef __hip_bfloat16 bf16;

#define N_USER 200000
#define N_ITEM 100000
#define NEDGE  1000000
#define HID    64

#define CHUNK 8192
#define NCI ((N_ITEM + CHUNK - 1) / CHUNK)   // 13 item chunks
#define NCU ((N_USER + CHUNK - 1) / CHUNK)   // 25 user chunks
#define NCB (NCI + NCU)                      // 38 total (fits one wave)

// ---------------------------------------------------------------------------
// Dtype-agnostic access: harness data may be fp32 or bf16 (detected at runtime
// each launch — no static state, graph-safe). Offsets are ELEMENT offsets.
// ---------------------------------------------------------------------------
__device__ __forceinline__ float bf2f(unsigned int u) {
    unsigned int x = u << 16;
    float f; __builtin_memcpy(&f, &x, 4); return f;
}
__device__ __forceinline__ float ldf(const void* p, long i, int isf32) {
    if (isf32) return ((const float*)p)[i];
    return bf2f(((const unsigned short*)p)[i]);
}
__device__ __forceinline__ void stf(void* p, long i, int isf32, float v) {
    if (isf32) ((float*)p)[i] = v;
    else       ((bf16*)p)[i] = (bf16)v;
}
// Load one edge_attr row (16 elems) vectorized: fp32 = 4x float4, bf16 = 2x int4.
__device__ __forceinline__ void load_row16(const void* ea, long e, int isf32, float* v) {
    if (isf32) {
        const float4* p = (const float4*)((const float*)ea + e * 16);
        float4 a = p[0], b = p[1], c = p[2], d = p[3];
        v[0]=a.x; v[1]=a.y; v[2]=a.z; v[3]=a.w;
        v[4]=b.x; v[5]=b.y; v[6]=b.z; v[7]=b.w;
        v[8]=c.x; v[9]=c.y; v[10]=c.z; v[11]=c.w;
        v[12]=d.x; v[13]=d.y; v[14]=d.z; v[15]=d.w;
    } else {
        const int4* q = (const int4*)((const unsigned short*)ea + e * 16);
        int4 s0 = q[0], s1 = q[1];
        unsigned int w;
        w=(unsigned)s0.x; v[0]=bf2f(w & 0xffff); v[1]=bf2f(w >> 16);
        w=(unsigned)s0.y; v[2]=bf2f(w & 0xffff); v[3]=bf2f(w >> 16);
        w=(unsigned)s0.z; v[4]=bf2f(w & 0xffff); v[5]=bf2f(w >> 16);
        w=(unsigned)s0.w; v[6]=bf2f(w & 0xffff); v[7]=bf2f(w >> 16);
        w=(unsigned)s1.x; v[8]=bf2f(w & 0xffff); v[9]=bf2f(w >> 16);
        w=(unsigned)s1.y; v[10]=bf2f(w & 0xffff); v[11]=bf2f(w >> 16);
        w=(unsigned)s1.z; v[12]=bf2f(w & 0xffff); v[13]=bf2f(w >> 16);
        w=(unsigned)s1.w; v[14]=bf2f(w & 0xffff); v[15]=bf2f(w >> 16);
    }
}

// fp32-vs-bf16 detector (R3-verified): fp32's interleaved mantissa halves hit
// biased exp >= 137 with p~0.46/word; true bf16 N(0,1) never does.
__global__ void detect_kernel(const void* __restrict__ x, int* __restrict__ flag) {
    const unsigned short* p = (const unsigned short*)x;
    int f = 0;
    for (int k = threadIdx.x; k < 512; k += 64) {
        int ex = (p[k] >> 7) & 0xFF;
        if (ex >= 137) f = 1;
    }
    unsigned long long b = __ballot(f != 0);
    if (threadIdx.x == 0) *flag = (b != 0ULL) ? 1 : 0;
}

// ---------------------------------------------------------------------------
// CSR build: fused dual histogram -> hierarchical 3-phase scan (full GPU,
// no serial chunk chain) -> fused dual scatter. cursor doubles as degree.
// R5 lesson: the 2-block serial-chunk scan ran 266 us at 0.28% occupancy
// (25 dependent chunks x ~10 us latency each). Hierarchical = all parallel.
// ---------------------------------------------------------------------------
__global__ __launch_bounds__(256) void hist2_kernel(
    const int* __restrict__ src, const int* __restrict__ dst,
    int* __restrict__ cnt_u, int* __restrict__ cnt_i, int E)
{
    int e = blockIdx.x * 256 + threadIdx.x;
    if (e < E) {
        atomicAdd(&cnt_u[src[e]], 1);
        atomicAdd(&cnt_i[dst[e]], 1);
    }
}

__device__ __forceinline__ int wave_incl_scan(int v, int lane) {
#pragma unroll
    for (int off = 1; off < 64; off <<= 1) {
        int t = __shfl_up(v, off, 64);
        if (lane >= off) v += t;
    }
    return v;
}

// Phase 1: per-chunk (8192 elems) block sums. Blocks 0..NCI-1 = item chunks,
// NCI..NCB-1 = user chunks.
__global__ __launch_bounds__(1024) void scan_part_kernel(
    const int* __restrict__ deg_i, int Ni,
    const int* __restrict__ deg_u, int Nu, int* __restrict__ bsums)
{
    __shared__ int swsum[16];
    int b = blockIdx.x;
    const int* deg; int N; int chunk;
    if (b < NCI) { deg = deg_i; N = Ni; chunk = b; }
    else         { deg = deg_u; N = Nu; chunk = b - NCI; }
    int tid = threadIdx.x, lane = tid & 63, wid = tid >> 6;
    int i0 = chunk * CHUNK + tid * 8;
    int tot = 0;
#pragma unroll
    for (int k = 0; k < 8; k++) { int i = i0 + k; tot += (i < N) ? deg[i] : 0; }
#pragma unroll
    for (int off = 1; off < 64; off <<= 1) tot += __shfl_xor(tot, off, 64);
    if (lane == 0) swsum[wid] = tot;
    __syncthreads();
    if (tid == 0) {
        int s = 0;
#pragma unroll
        for (int w = 0; w < 16; w++) s += swsum[w];
        bsums[b] = s;
    }
}

// Phase 2: one wave scans the 38 block sums (segmented at the item/user
// boundary via prefix subtraction) and writes both rowptr[N] totals.
__global__ void scan_mid_kernel(
    const int* __restrict__ bsums, int* __restrict__ boffs,
    int* __restrict__ rp_i, int Ni, int* __restrict__ rp_u, int Nu)
{
    int lane = threadIdx.x & 63;
    int v = (lane < NCB) ? bsums[lane] : 0;
    int incl = wave_incl_scan(v, lane);
    int ti = __shfl(incl, NCI - 1, 64);            // item segment total
    int tu = __shfl(incl, NCB - 1, 64) - ti;       // user segment total
    int off = incl - v - ((lane >= NCI) ? ti : 0); // segmented exclusive
    if (lane < NCB) boffs[lane] = off;
    if (lane == 0) { rp_i[Ni] = ti; rp_u[Nu] = tu; }
}

// Phase 3: re-read chunk, local scan, add block offset, write rowptr+cursor.
__global__ __launch_bounds__(1024) void scan_add_kernel(
    int* __restrict__ deg_i, int* __restrict__ rp_i, int Ni,
    int* __restrict__ deg_u, int* __restrict__ rp_u, int Nu,
    const int* __restrict__ boffs)
{
    __shared__ int swsum[16];
    int b = blockIdx.x;
    int* deg; int* rowptr; int N; int chunk;
    if (b < NCI) { deg = deg_i; rowptr = rp_i; N = Ni; chunk = b; }
    else         { deg = deg_u; rowptr = rp_u; N = Nu; chunk = b - NCI; }
    int tid = threadIdx.x, lane = tid & 63, wid = tid >> 6;
    int i0 = chunk * CHUNK + tid * 8;
    int v[8]; int tot = 0;
#pragma unroll
    for (int k = 0; k < 8; k++) { int i = i0 + k; v[k] = (i < N) ? deg[i] : 0; tot += v[k]; }
    int incl = wave_incl_scan(tot, lane);
    if (lane == 63) swsum[wid] = incl;
    __syncthreads();
    int wbase = 0;
    for (int jw = 0; jw < wid; jw++) wbase += swsum[jw];
    int exc = boffs[b] + wbase + incl - tot;
#pragma unroll
    for (int k = 0; k < 8; k++) {
        int i = i0 + k;
        if (i < N) { rowptr[i] = exc; deg[i] = exc; }   // deg becomes cursor
        exc += v[k];
    }
}

__global__ __launch_bounds__(256) void scatter2_kernel(
    const int* __restrict__ src, const int* __restrict__ dst,
    int* __restrict__ cur_u, int* __restrict__ cur_i,
    int2* __restrict__ perm_u, int2* __restrict__ perm_i, int E)
{
    int e = blockIdx.x * 256 + threadIdx.x;
    if (e >= E) return;
    int s = src[e], d = dst[e];
    int pu = atomicAdd(&cur_u[s], 1);
    perm_u[pu] = make_int2(e, d);
    int pi = atomicAdd(&cur_i[d], 1);
    perm_i[pi] = make_int2(e, s);
}

// ---------------------------------------------------------------------------
// Input projection (grid-stride): out[n,c] = relu(x[n,:]@W[:,c] + b[c]).
// Proven-fast template (never appears in top-5).
// ---------------------------------------------------------------------------
template<int K>
__global__ __launch_bounds__(256) void proj_kernel(
    const void* __restrict__ x, const void* __restrict__ W,
    const void* __restrict__ b, float* __restrict__ out, int N,
    const int* __restrict__ flagp)
{
    __shared__ float Ws[K * 64];
    __shared__ float xs[4][K];
    int isf32 = *flagp;
    int tid = threadIdx.x;
    for (int i = tid; i < K * 64; i += 256) Ws[i] = ldf(W, i, isf32);
    int r = tid >> 6, c = tid & 63;
    float bc = ldf(b, c, isf32);
    for (int row0 = blockIdx.x * 4; row0 < N; row0 += gridDim.x * 4) {
        __syncthreads();   // WAR on xs (and Ws staging, first iter)
        for (int i = tid; i < 4 * K; i += 256) {
            int rr = i / K, k = i - rr * K;
            int row = row0 + rr;
            xs[rr][k] = (row < N) ? ldf(x, (long)row * K + k, isf32) : 0.f;
        }
        __syncthreads();
        int row = row0 + r;
        float acc = bc;
#pragma unroll
        for (int k = 0; k < K; k++) acc = fmaf(xs[r][k], Ws[k * 64 + c], acc);
        if (row < N) out[(long)row * 64 + c] = fmaxf(acc, 0.f);
    }
}

// ---------------------------------------------------------------------------
// Phase A — edge aggregation only (R3-VERBATIM; proven ~95-130 us, no spill):
//   agg[n,c] = (1+eps)*h_dst[n,c] + sum_{j in CSR[n]} relu(h_src[src_j][c]
//              + ea[e_j]@We[:,c] + be[c])
// One wave per node, zero barriers in the loop. LDS 4.6 KB. Do NOT graft
// extra per-node tails here: R4's shfl-W1 tail changed regalloc and spilled
// the a0..a3 arrays in the EDGE loop (578 us, edge-proportional scratch
// traffic). __launch_bounds__(256,4) = proven 64-VGPR no-spill regime.
// ---------------------------------------------------------------------------
__global__ __launch_bounds__(256, 4) void agg_kernel(
    const float* __restrict__ h_src, const float* __restrict__ h_dst,
    const int* __restrict__ rowptr, const int2* __restrict__ perm,
    const void* __restrict__ ea,
    const void* __restrict__ We, long weoff, const void* __restrict__ be, long beoff,
    const void* __restrict__ eps, int conv,
    float* __restrict__ agg, int N, const int* __restrict__ flagp)
{
    __shared__ float Wes[16 * 64];
    __shared__ float bes[64];
    int isf32 = *flagp;
    int tid = threadIdx.x;
    for (int i = tid; i < 1024; i += 256) Wes[i] = ldf(We, weoff + i, isf32);
    if (tid < 64) bes[tid] = ldf(be, beoff + tid, isf32);
    __syncthreads();
    float eps1 = 1.f + ldf(eps, conv, isf32);
    int w = tid >> 6, c = tid & 63;
    float bec = bes[c];

    for (int n = blockIdx.x * 4 + w; n < N; n += gridDim.x * 4) {
        float hv = h_dst[(long)n * 64 + c];
        float acc = 0.f;
        int jb = rowptr[n], je = rowptr[n + 1];
        int j = jb;
        for (; j + 4 <= je; j += 4) {
            int2 p0 = perm[j], p1 = perm[j+1], p2 = perm[j+2], p3 = perm[j+3];
            float a0[16], a1[16], a2[16], a3[16];
            load_row16(ea, p0.x, isf32, a0);
            load_row16(ea, p1.x, isf32, a1);
            load_row16(ea, p2.x, isf32, a2);
            load_row16(ea, p3.x, isf32, a3);
            float h0 = h_src[(long)p0.y * 64 + c];
            float h1 = h_src[(long)p1.y * 64 + c];
            float h2 = h_src[(long)p2.y * 64 + c];
            float h3 = h_src[(long)p3.y * 64 + c];
            float m0 = bec, m1 = bec, m2 = bec, m3 = bec;
#pragma unroll
            for (int k = 0; k < 16; k++) {
                float wv = Wes[k * 64 + c];
                m0 = fmaf(a0[k], wv, m0); m1 = fmaf(a1[k], wv, m1);
                m2 = fmaf(a2[k], wv, m2); m3 = fmaf(a3[k], wv, m3);
            }
            acc += fmaxf(m0 + h0, 0.f); acc += fmaxf(m1 + h1, 0.f);
            acc += fmaxf(m2 + h2, 0.f); acc += fmaxf(m3 + h3, 0.f);
        }
        for (; j < je; j++) {
            int2 p0 = perm[j];
            float a0[16];
            load_row16(ea, p0.x, isf32, a0);
            float h0 = h_src[(long)p0.y * 64 + c];
            float m0 = bec;
#pragma unroll
            for (int k = 0; k < 16; k++) m0 = fmaf(a0[k], Wes[k * 64 + c], m0);
            acc += fmaxf(m0 + h0, 0.f);
        }
        agg[(long)n * 64 + c] = eps1 * hv + acc;
    }
}

// ---------------------------------------------------------------------------
// Phase B1 — W1 matvec: v[n,:] -> t[n,c] = relu(b1[c] + v@W1[:,c]).
// proj/w2-clone (the proven-fast single-weight 16.5 KB class), fp32 input,
// IN-PLACE safe (each block writes exactly the rows it staged).
// Grid 2048 (vs w2's 1024): deliberate A/B on grid size for this class.
// ---------------------------------------------------------------------------
__global__ __launch_bounds__(256) void w1_kernel(
    const float* __restrict__ v,
    const void* __restrict__ W1, const void* __restrict__ b1, long woff, long boff,
    float* __restrict__ t, int N, const int* __restrict__ flagp)
{
    __shared__ float Ws[4096];
    __shared__ float xs[4][64];
    int isf32 = *flagp;
    int tid = threadIdx.x;
    for (int i = tid; i < 4096; i += 256) Ws[i] = ldf(W1, woff + i, isf32);
    int r = tid >> 6, c = tid & 63;
    float bc = ldf(b1, boff + c, isf32);
    for (int row0 = blockIdx.x * 4; row0 < N; row0 += gridDim.x * 4) {
        __syncthreads();   // WAR on xs (and Ws staging, first iter)
        {
            int rr = tid >> 6, k = tid & 63;
            int row = row0 + rr;
            xs[rr][k] = (row < N) ? v[(long)row * 64 + k] : 0.f;
        }
        __syncthreads();
        int row = row0 + r;
        float acc = bc;
#pragma unroll
        for (int k = 0; k < 64; k++) acc = fmaf(xs[r][k], Ws[k * 64 + c], acc);
        if (row < N) t[(long)row * 64 + c] = fmaxf(acc, 0.f);
    }
}

// ---------------------------------------------------------------------------
// Phase B2 — W2 + optional residual + dtype store (proven ~150 us class).
// In-place safe.
// ---------------------------------------------------------------------------
template<int RESID>
__global__ __launch_bounds__(256) void w2_kernel(
    const float* __restrict__ t, const float* __restrict__ resid,
    const void* __restrict__ W2, const void* __restrict__ b2, long woff, long boff,
    float* __restrict__ outf, void* __restrict__ outv, long outoff,
    int N, const int* __restrict__ flagp)
{
    __shared__ float Ws[4096];
    __shared__ float xs[4][64];
    int isf32 = *flagp;
    int tid = threadIdx.x;
    for (int i = tid; i < 4096; i += 256) Ws[i] = ldf(W2, woff + i, isf32);
    int r = tid >> 6, c = tid & 63;
    float bc = ldf(b2, boff + c, isf32);
    for (int row0 = blockIdx.x * 4; row0 < N; row0 += gridDim.x * 4) {
        __syncthreads();   // WAR on xs (and Ws staging, first iter)
        {
            int rr = tid >> 6, k = tid & 63;
            int row = row0 + rr;
            xs[rr][k] = (row < N) ? t[(long)row * 64 + k] : 0.f;
        }
        __syncthreads();
        int row = row0 + r;
        float acc = bc;
#pragma unroll
        for (int k = 0; k < 64; k++) acc = fmaf(xs[r][k], Ws[k * 64 + c], acc);
        if (row < N) {
            float o = fmaxf(acc, 0.f);
            if (RESID) o += resid[(long)row * 64 + c];
            long base = (long)row * 64 + c;
            if (outv) stf(outv, outoff + base, isf32, o);
            else      outf[base] = o;
        }
    }
}

extern "C" void kernel_launch(void* const* d_in, const int* in_sizes, int n_in,
                              void* d_out, int out_size, void* d_ws, size_t ws_size,
                              hipStream_t stream)
{
    const void* x_user    = d_in[0];
    const void* x_item    = d_in[1];
    const void* edge_attr = d_in[2];
    const int*  src_idx   = (const int*)d_in[3];
    const int*  dst_idx   = (const int*)d_in[4];
    const void* Wp_user   = d_in[5];
    const void* bp_user   = d_in[6];
    const void* Wp_item   = d_in[7];
    const void* bp_item   = d_in[8];
    const void* eps       = d_in[9];
    const void* We        = d_in[10];
    const void* be        = d_in[11];
    const void* W1        = d_in[12];
    const void* b1        = d_in[13];
    const void* W2        = d_in[14];
    const void* b2        = d_in[15];

    // Workspace layout (4B elements, 256-aligned) — unchanged footprint
    // (+128 ints for scan block sums/offsets after perm_u).
    float* ws   = (float*)d_ws;
    int*  flag  = (int*)d_ws;
    float* h_u  = ws + 256;             // 12.8M
    float* h_i  = h_u + 12800000;       //  6.4M
    float* h_u2 = h_i + 6400000;        // 12.8M
    float* h_i2 = h_u2 + 12800000;      //  6.4M
    int* rowptr_i = (int*)(h_i2 + 6400000);   // 100,001 (pad 100,096)
    int* cursor_i = rowptr_i + 100096;        // 100,000 (pad 100,096); also deg
    int2* perm_i  = (int2*)(cursor_i + 100096);  // 1M int2
    int* rowptr_u = (int*)(perm_i + 1000000); // 200,001 (pad 200,192)
    int* cursor_u = rowptr_u + 200192;        // 200,000 (pad 200,192)
    int2* perm_u  = (int2*)(cursor_u + 200192);  // 1M int2
    int* bsums    = (int*)(perm_u + 1000000); // 64
    int* boffs    = bsums + 64;               // 64

    const int EG = (NEDGE + 255) / 256;

    detect_kernel<<<1, 64, 0, stream>>>(x_user, flag);

    // CSR build: both relations in single passes over the edge list.
    hipMemsetAsync(cursor_i, 0, N_ITEM * sizeof(int), stream);
    hipMemsetAsync(cursor_u, 0, N_USER * sizeof(int), stream);
    hist2_kernel<<<EG, 256, 0, stream>>>(src_idx, dst_idx, cursor_u, cursor_i, NEDGE);
    scan_part_kernel<<<NCB, 1024, 0, stream>>>(cursor_i, N_ITEM, cursor_u, N_USER, bsums);
    scan_mid_kernel<<<1, 64, 0, stream>>>(bsums, boffs, rowptr_i, N_ITEM, rowptr_u, N_USER);
    scan_add_kernel<<<NCB, 1024, 0, stream>>>(cursor_i, rowptr_i, N_ITEM,
                                              cursor_u, rowptr_u, N_USER, boffs);
    scatter2_kernel<<<EG, 256, 0, stream>>>(src_idx, dst_idx, cursor_u, cursor_i,
                                            perm_u, perm_i, NEDGE);

    // input projections
    proj_kernel<128><<<1024, 256, 0, stream>>>(x_user, Wp_user, bp_user, h_u, N_USER, flag);
    proj_kernel<64><<<1024, 256, 0, stream>>>(x_item, Wp_item, bp_item, h_i, N_ITEM, flag);

    // ---- layer 0 (no residual): agg -> v in h_*2; w1 in-place; w2 in-place.
    agg_kernel<<<2048, 256, 0, stream>>>(h_u, h_i, rowptr_i, perm_i, edge_attr,
        We, 0 * 1024, be, 0 * 64, eps, 0, h_i2, N_ITEM, flag);
    agg_kernel<<<2048, 256, 0, stream>>>(h_i, h_u, rowptr_u, perm_u, edge_attr,
        We, 1 * 1024, be, 1 * 64, eps, 1, h_u2, N_USER, flag);
    w1_kernel<<<2048, 256, 0, stream>>>(h_i2, W1, b1, 0 * 4096, 0 * 64, h_i2, N_ITEM, flag);
    w1_kernel<<<2048, 256, 0, stream>>>(h_u2, W1, b1, 1 * 4096, 1 * 64, h_u2, N_USER, flag);
    w2_kernel<0><<<1024, 256, 0, stream>>>(h_i2, nullptr,
        W2, b2, 0 * 4096, 0 * 64, h_i2, nullptr, 0, N_ITEM, flag);
    w2_kernel<0><<<1024, 256, 0, stream>>>(h_u2, nullptr,
        W2, b2, 1 * 4096, 1 * 64, h_u2, nullptr, 0, N_USER, flag);

    // ---- layer 1 (residual): agg reads h_*2 -> v in dead h_i / h_u;
    //      w1 in-place; w2 adds resid = h_*2, stores to d_out (flagged dtype).
    agg_kernel<<<2048, 256, 0, stream>>>(h_u2, h_i2, rowptr_i, perm_i, edge_attr,
        We, 2 * 1024, be, 2 * 64, eps, 2, h_i, N_ITEM, flag);
    agg_kernel<<<2048, 256, 0, stream>>>(h_i2, h_u2, rowptr_u, perm_u, edge_attr,
        We, 3 * 1024, be, 3 * 64, eps, 3, h_u, N_USER, flag);
    w1_kernel<<<2048, 256, 0, stream>>>(h_i, W1, b1, 2 * 4096, 2 * 64, h_i, N_ITEM, flag);
    w1_kernel<<<2048, 256, 0, stream>>>(h_u, W1, b1, 3 * 4096, 3 * 64, h_u, N_USER, flag);
    w2_kernel<1><<<1024, 256, 0, stream>>>(h_i, h_i2,
        W2, b2, 2 * 4096, 2 * 64, nullptr, d_out, (long)N_USER * HID, N_ITEM, flag);
    w2_kernel<1><<<1024, 256, 0, stream>>>(h_u, h_u2,
        W2, b2, 3 * 4096, 3 * 64, nullptr, d_out, 0, N_USER, flag);
}